// Round 4
// baseline (705.178 us; speedup 1.0000x reference)
//
#include <hip/hip_runtime.h>
#include <math.h>

namespace {
constexpr int kBatch = 32, kH = 56, kW = 56, kC = 192, kNH = 6, kWS = 7, kSS = 3;
constexpr int kL   = kH * kW;        // 3136
constexpr int kN   = kWS * kWS;      // 49
constexpr int kTok = kBatch * kL;    // 100352
constexpr int kNWin = kTok / kN;     // 2048 windows
constexpr float kEps   = 1e-3f;
constexpr float kScale = 0.17677669529663687f;  // HD^-0.5
}

typedef unsigned short u16;
typedef __attribute__((ext_vector_type(8))) short short8;   // 8 x bf16 (4 VGPRs)
typedef __attribute__((ext_vector_type(4))) float f32x4;    // MFMA accumulator

__device__ __forceinline__ float bf2f(u16 u) {
    return __uint_as_float(((unsigned int)u) << 16);
}
__device__ __forceinline__ u16 f2bf(float f) {  // round-to-nearest-even
    unsigned int x = __float_as_uint(f);
    return (u16)((x + 0x7FFFu + ((x >> 16) & 1u)) >> 16);
}
// tanh-approx GELU. |err vs exact erf-GELU| < 5e-4 everywhere; bf16 output
// rounding dominates. HW v_exp_f32 instead of libm erff.
__device__ __forceinline__ float gelu_f(float x) {
    float z = 0.7978845608028654f * x * (1.0f + 0.044715f * x * x);
    float t = 1.0f - 2.0f / (1.0f + __expf(2.0f * z));
    return 0.5f * x * (1.0f + t);
}

// ---------------------------------------------------------------------------
// LayerNorm over C=192 (fp32 in, bf16 out), one wave per token.
// ---------------------------------------------------------------------------
__global__ __launch_bounds__(256) void ln_kernel(
    const float* __restrict__ x, const float* __restrict__ gamma,
    const float* __restrict__ beta, u16* __restrict__ out, int do_shift)
{
    const int wave = threadIdx.x >> 6;
    const int lane = threadIdx.x & 63;
    const int tok = (blockIdx.x << 2) + wave;
    const float* xp = x + (size_t)tok * kC;
    float v0 = xp[lane], v1 = xp[lane + 64], v2 = xp[lane + 128];
    float s  = v0 + v1 + v2;
    float sq = v0 * v0 + v1 * v1 + v2 * v2;
    #pragma unroll
    for (int off = 32; off > 0; off >>= 1) {
        s  += __shfl_down(s, off, 64);
        sq += __shfl_down(sq, off, 64);
    }
    s  = __shfl(s, 0, 64);
    sq = __shfl(sq, 0, 64);
    const float mean = s * (1.0f / kC);
    const float var  = sq * (1.0f / kC) - mean * mean;
    const float inv  = rsqrtf(var + kEps);
    size_t orow;
    if (do_shift) {
        const int b = tok / kL, hw = tok % kL;
        const int h = hw / kW, w = hw % kW;
        const int hs = (h + kH - kSS) % kH;
        const int ws = (w + kW - kSS) % kW;
        const int wh = hs / kWS, ii = hs % kWS;
        const int ww = ws / kWS, jj = ws % kWS;
        orow = (size_t)(b * 64 + wh * 8 + ww) * kN + (ii * kWS + jj);
    } else {
        orow = tok;
    }
    u16* op = out + orow * kC;
    op[lane]       = f2bf((v0 - mean) * inv * gamma[lane]       + beta[lane]);
    op[lane + 64]  = f2bf((v1 - mean) * inv * gamma[lane + 64]  + beta[lane + 64]);
    op[lane + 128] = f2bf((v2 - mean) * inv * gamma[lane + 128] + beta[lane + 128]);
}

// ---------------------------------------------------------------------------
// Weight prep. qkv: fp32 (192 x 576) -> bf16 n-major (576 x 192), q-cols
// pre-scaled by kScale.
// ---------------------------------------------------------------------------
__global__ __launch_bounds__(256) void wprep_qkv(
    const float* __restrict__ w, u16* __restrict__ wt)
{
    const int idx = blockIdx.x * 256 + threadIdx.x;
    if (idx >= 576 * 192) return;
    const int n = idx / 192, k = idx - n * 192;
    float v = w[(size_t)k * 576 + n];
    if (n < 192) v *= kScale;
    wt[idx] = f2bf(v);
}

__global__ __launch_bounds__(256) void wprep_rest(
    const float* __restrict__ pw, const float* __restrict__ f1w,
    const float* __restrict__ f2w, u16* __restrict__ proj_t,
    u16* __restrict__ f1_t, u16* __restrict__ f2_t)
{
    int idx = blockIdx.x * 256 + threadIdx.x;
    if (idx < 36864) {
        const int n = idx / 192, k = idx - n * 192;
        proj_t[idx] = f2bf(pw[(size_t)k * 192 + n]);
        return;
    }
    idx -= 36864;
    if (idx < 147456) {
        const int n = idx / 192, k = idx - n * 192;
        f1_t[idx] = f2bf(f1w[(size_t)k * 768 + n]);
        return;
    }
    idx -= 147456;
    if (idx < 147456) {
        const int n = idx / 768, k = idx - n * 768;
        f2_t[idx] = f2bf(f2w[(size_t)k * 192 + n]);
    }
}

// ---------------------------------------------------------------------------
// Bias+mask table T[cls][head][n][m] (mask folded, used as MFMA C-init) and
// scaled qkv bias copy (q-part * kScale).
// ---------------------------------------------------------------------------
__global__ __launch_bounds__(256) void prep_bm(
    const float* __restrict__ btab, const float* __restrict__ qkv_b,
    float* __restrict__ T, float* __restrict__ qkv_bs)
{
    const int idx = blockIdx.x * 256 + threadIdx.x;
    if (idx < 576) qkv_bs[idx] = (idx < 192) ? qkv_b[idx] * kScale : qkv_b[idx];
    if (idx >= 4 * 6 * 49 * 49) return;
    const int m = idx % 49, n = (idx / 49) % 49;
    const int head = (idx / 2401) % 6, cls = idx / (2401 * 6);
    const int i1 = n / 7, j1 = n % 7, i2 = m / 7, j2 = m % 7;
    float v = btab[((i1 - i2 + 6) * 13 + (j1 - j2 + 6)) * kNH + head];
    const int whE = cls >> 1, wwE = cls & 1;
    const int r1 = (whE ? (i1 < 4 ? 1 : 2) : 0) * 3 + (wwE ? (j1 < 4 ? 1 : 2) : 0);
    const int r2 = (whE ? (i2 < 4 ? 1 : 2) : 0) * 3 + (wwE ? (j2 < 4 ? 1 : 2) : 0);
    if (r1 != r2) v -= 100.f;
    T[idx] = v;
}

// ---------------------------------------------------------------------------
// MFMA GEMM with LDS-staged A: out(M x Nn) = A_bf16(M x K) @ Bt + bias.
// MODE 0: bf16 out   2: scatter+residual(aux) fp32 out
// MODE 5 (qkv): j<2 -> bf16 q,k into rows of 576; j==2 -> scatter v
//               TRANSPOSED into vt[(win*6+head)*32 + d][64] (aux2).
// v4: register double-buffer of B-frags (next-ks loads issued before the
// MFMA cluster) + __launch_bounds__(256,4) (VGPR cap 128, need ~110) so the
// compiler keeps the prefetch registers. Previously every ks-step stalled
// ~200cy on L2 B-loads (VGPR 88 = no prefetch regs allocated).
// ---------------------------------------------------------------------------
template <int MODE, int K, int NJ>
__global__ __launch_bounds__(256, 4) void gemm_mfma(
    const u16* __restrict__ A, const u16* __restrict__ Bt, int ldb,
    const float* __restrict__ bias, const float* __restrict__ aux,
    void* __restrict__ outv, u16* __restrict__ vt = nullptr)
{
    constexpr int Nn = NJ * 192;
    constexpr int Kp = K + 8;
    __shared__ u16 As[64 * Kp];
    const int tid  = threadIdx.x;
    const int wave = tid >> 6, lane = tid & 63;
    const int quad = lane >> 4, l15 = lane & 15;
    const int m0 = blockIdx.x * 64;

    {
        const u16* src = A + (size_t)m0 * K;
        #pragma unroll
        for (int i = tid; i < 64 * K / 8; i += 256) {
            const int e = i * 8;
            const int r = e / K, c = e - r * K;
            *(short8*)&As[r * Kp + c] = *(const short8*)(src + e);
        }
    }
    __syncthreads();

    #pragma unroll
    for (int j = 0; j < NJ; ++j) {
        const int nb0 = j * 192 + wave * 48;
        const u16* Bbase = Bt + (size_t)(nb0 + l15) * ldb + quad * 8;
        f32x4 acc[4][3] = {};
        short8 bc[3], bn[3];
        #pragma unroll
        for (int t = 0; t < 3; ++t)
            bc[t] = *(const short8*)(Bbase + (size_t)t * 16 * ldb);
        #pragma unroll
        for (int ks = 0; ks < K / 32; ++ks) {
            if (ks + 1 < K / 32) {
                #pragma unroll
                for (int t = 0; t < 3; ++t)
                    bn[t] = *(const short8*)(Bbase + (size_t)t * 16 * ldb +
                                             (ks + 1) * 32);
            }
            short8 a[4];
            #pragma unroll
            for (int i = 0; i < 4; ++i)
                a[i] = *(const short8*)&As[(i * 16 + l15) * Kp + ks * 32 + quad * 8];
            #pragma unroll
            for (int i = 0; i < 4; ++i)
                #pragma unroll
                for (int t = 0; t < 3; ++t)
                    acc[i][t] = __builtin_amdgcn_mfma_f32_16x16x32_bf16(
                        a[i], bc[t], acc[i][t], 0, 0, 0);
            if (ks + 1 < K / 32) {
                #pragma unroll
                for (int t = 0; t < 3; ++t) bc[t] = bn[t];
            }
        }
        float bcol[3] = {0.f, 0.f, 0.f};
        {
            #pragma unroll
            for (int t = 0; t < 3; ++t) bcol[t] = bias[nb0 + t * 16 + l15];
        }
        #pragma unroll
        for (int i = 0; i < 4; ++i) {
            #pragma unroll
            for (int reg = 0; reg < 4; ++reg) {
                const int r = m0 + i * 16 + quad * 4 + reg;
                if (MODE == 2) {
                    const int win = r / kN, n = r % kN;
                    const int b = win >> 6, wi = win & 63;
                    const int wh = wi >> 3, ww = wi & 7;
                    const int i1 = n / kWS, j1 = n % kWS;
                    const int h = (wh * kWS + i1 + kSS) % kH;
                    const int w = (ww * kWS + j1 + kSS) % kW;
                    const size_t drow = ((size_t)b * kL + h * kW + w) * kC;
                    #pragma unroll
                    for (int t = 0; t < 3; ++t) {
                        const int c = nb0 + t * 16 + l15;
                        const size_t dest = drow + c;
                        ((float*)outv)[dest] = acc[i][t][reg] + bcol[t] + aux[dest];
                    }
                } else if (MODE == 5 && j == 2) {
                    // scatter v transposed: row win*6*32 + head*32 + d, col n
                    const int win = r / kN, n = r - win * kN;
                    #pragma unroll
                    for (int t = 0; t < 3; ++t) {
                        const int d = nb0 - 384 + t * 16 + l15;
                        const size_t off =
                            ((size_t)win * 192 + d) * 64 + n;  // 192 = 6*32
                        vt[off] = f2bf(acc[i][t][reg] + bcol[t]);
                    }
                } else {
                    #pragma unroll
                    for (int t = 0; t < 3; ++t) {
                        const int c = nb0 + t * 16 + l15;
                        float v = acc[i][t][reg] + bcol[t];
                        ((u16*)outv)[(size_t)r * Nn + c] = f2bf(v);
                    }
                }
            }
        }
    }
}

// ---------------------------------------------------------------------------
// Fused LN2 + MLP: out = x1 + fc2(gelu(fc1(LN(x1)))), one block per 64 tokens.
// v4: back to the measured-best v1 shape (256 thr, 4 waves, acc[4][3]/phase)
// with two changes driven by the latency-bound signature:
//  (a) hidden processed in FOUR 192-col chunks -> Hs shrinks 50.2->25.6 KB,
//      total LDS 51.2 KB -> 3 blocks/CU (was 2): +50% resident waves.
//  (b) register double-buffer of B-frags in fc1 and fc2 (see gemm_mfma).
// LN uses 16-lanes-per-row float4 loads (4 rounds instead of 16).
// (256,3): VGPR cap ~168, est. need ~155. Round-2 lesson: never cap below
// the live-state requirement (spill traffic >> occupancy gain).
// ---------------------------------------------------------------------------
__global__ __launch_bounds__(256, 3) void mlp_fused(
    float* __restrict__ out,          // holds x1 on entry; final out (RMW)
    const float* __restrict__ gamma, const float* __restrict__ beta,
    const u16* __restrict__ f1_t, const float* __restrict__ fc1_b,
    const u16* __restrict__ f2_t, const float* __restrict__ fc2_b)
{
    constexpr int Kp = 200;   // As row pitch (u16): 192 + 8
    constexpr int Hp = 200;   // Hs row pitch (u16): 192 + 8
    __shared__ u16 As[64 * Kp];   // 25600 B
    __shared__ u16 Hs[64 * Hp];   // 25600 B
    const int tid  = threadIdx.x;
    const int wave = tid >> 6, lane = tid & 63;
    const int quad = lane >> 4, l15 = lane & 15;
    const int m0 = blockIdx.x * 64;

    // ---- LN: 16 lanes/row, 4 rows/wave/round, 4 rounds -> As bf16 ----
    {
        float gv[12], bv[12];
        #pragma unroll
        for (int j = 0; j < 12; ++j) {
            gv[j] = gamma[l15 * 12 + j];
            bv[j] = beta[l15 * 12 + j];
        }
        #pragma unroll
        for (int it = 0; it < 4; ++it) {
            const int r = it * 16 + wave * 4 + quad;
            const float* xp = out + (size_t)(m0 + r) * kC + l15 * 12;
            float4 u0 = *(const float4*)(xp);
            float4 u1 = *(const float4*)(xp + 4);
            float4 u2 = *(const float4*)(xp + 8);
            float v[12] = {u0.x, u0.y, u0.z, u0.w, u1.x, u1.y, u1.z, u1.w,
                           u2.x, u2.y, u2.z, u2.w};
            float s = 0.f, sq = 0.f;
            #pragma unroll
            for (int j = 0; j < 12; ++j) { s += v[j]; sq += v[j] * v[j]; }
            #pragma unroll
            for (int off = 1; off < 16; off <<= 1) {
                s  += __shfl_xor(s, off, 64);
                sq += __shfl_xor(sq, off, 64);
            }
            const float mean = s * (1.0f / kC);
            const float inv  = rsqrtf(sq * (1.0f / kC) - mean * mean + kEps);
            unsigned* ap = (unsigned*)&As[r * Kp + l15 * 12];
            #pragma unroll
            for (int j = 0; j < 6; ++j) {
                float a0 = (v[2 * j]     - mean) * inv * gv[2 * j]     + bv[2 * j];
                float a1 = (v[2 * j + 1] - mean) * inv * gv[2 * j + 1] + bv[2 * j + 1];
                ap[j] = (unsigned)f2bf(a0) | ((unsigned)f2bf(a1) << 16);
            }
        }
    }
    __syncthreads();

    f32x4 acc2[4][3] = {};   // fc2 accumulator, persists across chunks
    for (int c = 0; c < 4; ++c) {
        // ---- fc1: rows 0..63 x hidden cols [c*192 + wave*48, +48) ----
        f32x4 acc1[4][3] = {};
        {
            const u16* B1 = f1_t + (size_t)(c * 192 + wave * 48 + l15) * 192 + quad * 8;
            short8 bc[3], bn[3];
            #pragma unroll
            for (int t = 0; t < 3; ++t)
                bc[t] = *(const short8*)(B1 + (size_t)t * 16 * 192);
            #pragma unroll
            for (int ks = 0; ks < 6; ++ks) {
                if (ks < 5) {
                    #pragma unroll
                    for (int t = 0; t < 3; ++t)
                        bn[t] = *(const short8*)(B1 + (size_t)t * 16 * 192 +
                                                 (ks + 1) * 32);
                }
                short8 a[4];
                #pragma unroll
                for (int i = 0; i < 4; ++i)
                    a[i] = *(const short8*)&As[(i * 16 + l15) * Kp + ks * 32 + quad * 8];
                #pragma unroll
                for (int i = 0; i < 4; ++i)
                    #pragma unroll
                    for (int t = 0; t < 3; ++t)
                        acc1[i][t] = __builtin_amdgcn_mfma_f32_16x16x32_bf16(
                            a[i], bc[t], acc1[i][t], 0, 0, 0);
                if (ks < 5) {
                    #pragma unroll
                    for (int t = 0; t < 3; ++t) bc[t] = bn[t];
                }
            }
        }
        __syncthreads();   // c>0: all waves done reading Hs chunk c-1
        // ---- bias + GELU -> Hs (bf16) ----
        #pragma unroll
        for (int t = 0; t < 3; ++t) {
            const int cc = wave * 48 + t * 16 + l15;
            const float bb = fc1_b[c * 192 + cc];
            #pragma unroll
            for (int i = 0; i < 4; ++i) {
                #pragma unroll
                for (int reg = 0; reg < 4; ++reg) {
                    const int r = i * 16 + quad * 4 + reg;
                    Hs[r * Hp + cc] = f2bf(gelu_f(acc1[i][t][reg] + bb));
                }
            }
        }
        __syncthreads();
        // ---- fc2: rows 0..63 x out cols [wave*48,+48), K=192 from Hs ----
        {
            const u16* B2 = f2_t + (size_t)(wave * 48 + l15) * 768 + c * 192 + quad * 8;
            short8 bc[3], bn[3];
            #pragma unroll
            for (int t = 0; t < 3; ++t)
                bc[t] = *(const short8*)(B2 + (size_t)t * 16 * 768);
            #pragma unroll
            for (int ks = 0; ks < 6; ++ks) {
                if (ks < 5) {
                    #pragma unroll
                    for (int t = 0; t < 3; ++t)
                        bn[t] = *(const short8*)(B2 + (size_t)t * 16 * 768 +
                                                 (ks + 1) * 32);
                }
                short8 a[4];
                #pragma unroll
                for (int i = 0; i < 4; ++i)
                    a[i] = *(const short8*)&Hs[(i * 16 + l15) * Hp + ks * 32 + quad * 8];
                #pragma unroll
                for (int i = 0; i < 4; ++i)
                    #pragma unroll
                    for (int t = 0; t < 3; ++t)
                        acc2[i][t] = __builtin_amdgcn_mfma_f32_16x16x32_bf16(
                            a[i], bc[t], acc2[i][t], 0, 0, 0);
                if (ks < 5) {
                    #pragma unroll
                    for (int t = 0; t < 3; ++t) bc[t] = bn[t];
                }
            }
        }
    }
    // ---- epilogue: out = x1 + acc2 + fc2_b ----
    #pragma unroll
    for (int t = 0; t < 3; ++t) {
        const int cc = wave * 48 + t * 16 + l15;
        const float bb = fc2_b[cc];
        #pragma unroll
        for (int i = 0; i < 4; ++i) {
            #pragma unroll
            for (int reg = 0; reg < 4; ++reg) {
                const int r = m0 + i * 16 + quad * 4 + reg;
                float* p = out + (size_t)r * kC + cc;
                *p = acc2[i][t][reg] + bb + *p;
            }
        }
    }
}

// ---------------------------------------------------------------------------
// MFMA window attention v2: ONE WAVE per (window, head).
// ---------------------------------------------------------------------------
__global__ __launch_bounds__(256) void attn_mfma(
    const u16* __restrict__ qkv, const u16* __restrict__ vt,
    const float* __restrict__ T, u16* __restrict__ out)
{
    __shared__ u16 Ps[4][64][72];
    const int tid = threadIdx.x;
    const int wave = tid >> 6, lane = tid & 63;
    const int quad = lane >> 4, l15 = lane & 15;
    const int pair = blockIdx.x * 4 + wave;
    const int win = pair / 6, head = pair - win * 6;
    const int wi = win & 63;
    const int cls = (((wi >> 3) == 7) ? 2 : 0) + (((wi & 7) == 7) ? 1 : 0);
    const float* Tb = T + (size_t)(cls * 6 + head) * 49 * 49;

    const u16* base = qkv + (size_t)win * 49 * 576 + head * 32 + quad * 8;
    short8 zz = {};
    short8 qa[4], kb[4];
    #pragma unroll
    for (int i = 0; i < 4; ++i) {
        const int n = i * 16 + l15;
        qa[i] = (n < 49) ? *(const short8*)(base + (size_t)n * 576) : zz;
        kb[i] = (n < 49) ? *(const short8*)(base + (size_t)n * 576 + 192) : zz;
    }
    f32x4 acc[4][4];
    #pragma unroll
    for (int i = 0; i < 4; ++i) {
        #pragma unroll
        for (int reg = 0; reg < 4; ++reg) {
            const int n = i * 16 + quad * 4 + reg;
            const bool nv = (n < 49);
            const float* Trow = Tb + (nv ? n : 0) * 49;
            #pragma unroll
            for (int j = 0; j < 3; ++j)
                acc[i][j][reg] = nv ? Trow[j * 16 + l15] : 0.f;
            acc[i][3][reg] = (nv && l15 == 0) ? Trow[48] : -30000.f;
        }
    }
    #pragma unroll
    for (int i = 0; i < 4; ++i)
        #pragma unroll
        for (int j = 0; j < 4; ++j)
            acc[i][j] = __builtin_amdgcn_mfma_f32_16x16x32_bf16(
                qa[i], kb[j], acc[i][j], 0, 0, 0);
    float rowinv[4][4];
    #pragma unroll
    for (int i = 0; i < 4; ++i) {
        #pragma unroll
        for (int reg = 0; reg < 4; ++reg) {
            const int n = i * 16 + quad * 4 + reg;
            float e0 = __expf(acc[i][0][reg]), e1 = __expf(acc[i][1][reg]);
            float e2 = __expf(acc[i][2][reg]), e3 = __expf(acc[i][3][reg]);
            float sum = e0 + e1 + e2 + e3;
            #pragma unroll
            for (int off = 1; off < 16; off <<= 1)
                sum += __shfl_xor(sum, off, 64);
            rowinv[i][reg] = 1.0f / sum;
            Ps[wave][n][0 * 16 + l15] = f2bf(e0);
            Ps[wave][n][1 * 16 + l15] = f2bf(e1);
            Ps[wave][n][2 * 16 + l15] = f2bf(e2);
            Ps[wave][n][3 * 16 + l15] = f2bf(e3);
        }
    }
    const u16* vb_base = vt + ((size_t)pair * 32 + l15) * 64 + quad * 8;
    f32x4 o[4][2] = {};
    #pragma unroll
    for (int ks = 0; ks < 2; ++ks) {
        short8 pa[4], vb[2];
        #pragma unroll
        for (int i = 0; i < 4; ++i)
            pa[i] = *(const short8*)&Ps[wave][i * 16 + l15][ks * 32 + quad * 8];
        #pragma unroll
        for (int t = 0; t < 2; ++t)
            vb[t] = *(const short8*)(vb_base + (size_t)t * 16 * 64 + ks * 32);
        #pragma unroll
        for (int i = 0; i < 4; ++i)
            #pragma unroll
            for (int t = 0; t < 2; ++t)
                o[i][t] = __builtin_amdgcn_mfma_f32_16x16x32_bf16(
                    pa[i], vb[t], o[i][t], 0, 0, 0);
    }
    u16* obase = out + (size_t)win * 49 * 192 + head * 32;
    #pragma unroll
    for (int i = 0; i < 4; ++i) {
        #pragma unroll
        for (int reg = 0; reg < 4; ++reg) {
            const int n = i * 16 + quad * 4 + reg;
            if (n < 49) {
                const float inv = rowinv[i][reg];
                obase[(size_t)n * 192 + l15]      = f2bf(o[i][0][reg] * inv);
                obase[(size_t)n * 192 + 16 + l15] = f2bf(o[i][1][reg] * inv);
            }
        }
    }
}

// ---------------------------------------------------------------------------
extern "C" void kernel_launch(void* const* d_in, const int* in_sizes, int n_in,
                              void* d_out, int out_size, void* d_ws, size_t ws_size,
                              hipStream_t stream)
{
    const float* x      = (const float*)d_in[0];
    const float* gamma1 = (const float*)d_in[1];
    const float* beta1  = (const float*)d_in[2];
    const float* qkv_w  = (const float*)d_in[3];
    const float* qkv_b  = (const float*)d_in[4];
    const float* proj_w = (const float*)d_in[5];
    const float* proj_b = (const float*)d_in[6];
    const float* btab   = (const float*)d_in[7];
    const float* gamma2 = (const float*)d_in[8];
    const float* beta2  = (const float*)d_in[9];
    const float* fc1_w  = (const float*)d_in[10];
    const float* fc1_b  = (const float*)d_in[11];
    const float* fc2_w  = (const float*)d_in[12];
    const float* fc2_b  = (const float*)d_in[13];
    float* out = (float*)d_out;

    // ws budget EXACTLY kTok*768*2 B. d_out (77 MB fp32) doubles as scratch
    // until the proj epilogue: qkv_t | bm_tab | qkv_bs | vT(50.3 MB).
    u16* buf_a = (u16*)d_ws;                      // kTok*192 bf16
    u16* buf_b = buf_a + (size_t)kTok * 192;      // kTok*576 bf16 (q,k used)
    u16* qkv_t = (u16*)d_out;                     // 110592 u16
    float* bm_tab = (float*)d_out + 55296;        // 57624 f32
    float* qkv_bs = bm_tab + 57624;               // 576 f32
    u16* vT = (u16*)d_out + 230400;               // 2048*6*32*64 u16, 16B-aligned
    u16* wt2   = (u16*)d_ws + (size_t)kTok * 768 - 331776;
    u16* proj_t = wt2;
    u16* f1_t   = wt2 + 36864;
    u16* f2_t   = f1_t + 147456;

    // 0) prep: qkv weights (q pre-scaled), bias+mask table, scaled qkv bias
    wprep_qkv<<<(110592 + 255) / 256, 256, 0, stream>>>(qkv_w, qkv_t);
    prep_bm<<<(57624 + 255) / 256, 256, 0, stream>>>(btab, qkv_b, bm_tab, qkv_bs);
    // 1) LN1 + cyclic shift + window partition
    ln_kernel<<<kTok / 4, 256, 0, stream>>>(x, gamma1, beta1, buf_a, 1);
    // 2) qkv GEMM -> q,k rows in buf_b; v scattered transposed into vT
    gemm_mfma<5, 192, 3><<<kTok / 64, 256, 0, stream>>>(
        buf_a, qkv_t, 192, qkv_bs, nullptr, buf_b, vT);
    // 3) MFMA window attention -> buf_a (bf16)
    attn_mfma<<<(kNWin * kNH) / 4, 256, 0, stream>>>(buf_b, vT, bm_tab, buf_a);
    // 4) remaining weight prep into buf_b tail (qkv dead now)
    wprep_rest<<<(331776 + 255) / 256, 256, 0, stream>>>(
        proj_w, fc1_w, fc2_w, proj_t, f1_t, f2_t);
    // 5) proj GEMM + window reverse + unshift + residual(x) -> x1 in d_out
    gemm_mfma<2, 192, 1><<<kTok / 64, 256, 0, stream>>>(
        buf_a, proj_t, 192, proj_b, x, out);
    // 6) fused LN2 + fc1 + GELU + fc2 + residual, hidden in 4 LDS chunks
    mlp_fused<<<kTok / 64, 256, 0, stream>>>(
        out, gamma2, beta2, f1_t, fc1_b, f2_t, fc2_b);
}

// Round 5
// 528.981 us; speedup vs baseline: 1.3331x; 1.3331x over previous
//
#include <hip/hip_runtime.h>
#include <math.h>

namespace {
constexpr int kBatch = 32, kH = 56, kW = 56, kC = 192, kNH = 6, kWS = 7, kSS = 3;
constexpr int kL   = kH * kW;        // 3136
constexpr int kN   = kWS * kWS;      // 49
constexpr int kTok = kBatch * kL;    // 100352
constexpr int kNWin = kTok / kN;     // 2048 windows
constexpr float kEps   = 1e-3f;
constexpr float kScale = 0.17677669529663687f;  // HD^-0.5
}

typedef unsigned short u16;
typedef __attribute__((ext_vector_type(8))) short short8;   // 8 x bf16 (4 VGPRs)
typedef __attribute__((ext_vector_type(4))) float f32x4;    // MFMA accumulator

__device__ __forceinline__ float bf2f(u16 u) {
    return __uint_as_float(((unsigned int)u) << 16);
}
__device__ __forceinline__ u16 f2bf(float f) {  // round-to-nearest-even
    unsigned int x = __float_as_uint(f);
    return (u16)((x + 0x7FFFu + ((x >> 16) & 1u)) >> 16);
}
// tanh-approx GELU. |err vs exact erf-GELU| < 5e-4 everywhere; bf16 output
// rounding dominates. HW v_exp_f32 instead of libm erff.
__device__ __forceinline__ float gelu_f(float x) {
    float z = 0.7978845608028654f * x * (1.0f + 0.044715f * x * x);
    float t = 1.0f - 2.0f / (1.0f + __expf(2.0f * z));
    return 0.5f * x * (1.0f + t);
}

// ---------------------------------------------------------------------------
// LayerNorm over C=192 (fp32 in, bf16 out), one wave per token.
// ---------------------------------------------------------------------------
__global__ __launch_bounds__(256) void ln_kernel(
    const float* __restrict__ x, const float* __restrict__ gamma,
    const float* __restrict__ beta, u16* __restrict__ out, int do_shift)
{
    const int wave = threadIdx.x >> 6;
    const int lane = threadIdx.x & 63;
    const int tok = (blockIdx.x << 2) + wave;
    const float* xp = x + (size_t)tok * kC;
    float v0 = xp[lane], v1 = xp[lane + 64], v2 = xp[lane + 128];
    float s  = v0 + v1 + v2;
    float sq = v0 * v0 + v1 * v1 + v2 * v2;
    #pragma unroll
    for (int off = 32; off > 0; off >>= 1) {
        s  += __shfl_down(s, off, 64);
        sq += __shfl_down(sq, off, 64);
    }
    s  = __shfl(s, 0, 64);
    sq = __shfl(sq, 0, 64);
    const float mean = s * (1.0f / kC);
    const float var  = sq * (1.0f / kC) - mean * mean;
    const float inv  = rsqrtf(var + kEps);
    size_t orow;
    if (do_shift) {
        const int b = tok / kL, hw = tok % kL;
        const int h = hw / kW, w = hw % kW;
        const int hs = (h + kH - kSS) % kH;
        const int ws = (w + kW - kSS) % kW;
        const int wh = hs / kWS, ii = hs % kWS;
        const int ww = ws / kWS, jj = ws % kWS;
        orow = (size_t)(b * 64 + wh * 8 + ww) * kN + (ii * kWS + jj);
    } else {
        orow = tok;
    }
    u16* op = out + orow * kC;
    op[lane]       = f2bf((v0 - mean) * inv * gamma[lane]       + beta[lane]);
    op[lane + 64]  = f2bf((v1 - mean) * inv * gamma[lane + 64]  + beta[lane + 64]);
    op[lane + 128] = f2bf((v2 - mean) * inv * gamma[lane + 128] + beta[lane + 128]);
}

// ---------------------------------------------------------------------------
// Weight prep. qkv: fp32 (192 x 576) -> bf16 n-major (576 x 192), q-cols
// pre-scaled by kScale.
// ---------------------------------------------------------------------------
__global__ __launch_bounds__(256) void wprep_qkv(
    const float* __restrict__ w, u16* __restrict__ wt)
{
    const int idx = blockIdx.x * 256 + threadIdx.x;
    if (idx >= 576 * 192) return;
    const int n = idx / 192, k = idx - n * 192;
    float v = w[(size_t)k * 576 + n];
    if (n < 192) v *= kScale;
    wt[idx] = f2bf(v);
}

__global__ __launch_bounds__(256) void wprep_rest(
    const float* __restrict__ pw, const float* __restrict__ f1w,
    const float* __restrict__ f2w, u16* __restrict__ proj_t,
    u16* __restrict__ f1_t, u16* __restrict__ f2_t)
{
    int idx = blockIdx.x * 256 + threadIdx.x;
    if (idx < 36864) {
        const int n = idx / 192, k = idx - n * 192;
        proj_t[idx] = f2bf(pw[(size_t)k * 192 + n]);
        return;
    }
    idx -= 36864;
    if (idx < 147456) {
        const int n = idx / 192, k = idx - n * 192;
        f1_t[idx] = f2bf(f1w[(size_t)k * 768 + n]);
        return;
    }
    idx -= 147456;
    if (idx < 147456) {
        const int n = idx / 768, k = idx - n * 768;
        f2_t[idx] = f2bf(f2w[(size_t)k * 192 + n]);
    }
}

// ---------------------------------------------------------------------------
// Bias+mask table T[cls][head][n][m] (mask folded, used as MFMA C-init) and
// scaled qkv bias copy (q-part * kScale).
// ---------------------------------------------------------------------------
__global__ __launch_bounds__(256) void prep_bm(
    const float* __restrict__ btab, const float* __restrict__ qkv_b,
    float* __restrict__ T, float* __restrict__ qkv_bs)
{
    const int idx = blockIdx.x * 256 + threadIdx.x;
    if (idx < 576) qkv_bs[idx] = (idx < 192) ? qkv_b[idx] * kScale : qkv_b[idx];
    if (idx >= 4 * 6 * 49 * 49) return;
    const int m = idx % 49, n = (idx / 49) % 49;
    const int head = (idx / 2401) % 6, cls = idx / (2401 * 6);
    const int i1 = n / 7, j1 = n % 7, i2 = m / 7, j2 = m % 7;
    float v = btab[((i1 - i2 + 6) * 13 + (j1 - j2 + 6)) * kNH + head];
    const int whE = cls >> 1, wwE = cls & 1;
    const int r1 = (whE ? (i1 < 4 ? 1 : 2) : 0) * 3 + (wwE ? (j1 < 4 ? 1 : 2) : 0);
    const int r2 = (whE ? (i2 < 4 ? 1 : 2) : 0) * 3 + (wwE ? (j2 < 4 ? 1 : 2) : 0);
    if (r1 != r2) v -= 100.f;
    T[idx] = v;
}

// ---------------------------------------------------------------------------
// MFMA GEMM with LDS-staged A: out(M x Nn) = A_bf16(M x K) @ Bt + bias.
// MODE 0: bf16 out   2: scatter+residual(aux) fp32 out
// MODE 5 (qkv): j<2 -> bf16 q,k into rows of 576; j==2 -> scatter v
//               TRANSPOSED into vt[(win*6+head)*32 + d][64] (aux2).
// NOTE: plain __launch_bounds__(256) ONLY. Rounds 2-4 showed any min-occ
// second arg clamps VGPR below live state (88->64) -> ~1 GB spill traffic.
// ---------------------------------------------------------------------------
template <int MODE, int K, int NJ>
__global__ __launch_bounds__(256) void gemm_mfma(
    const u16* __restrict__ A, const u16* __restrict__ Bt, int ldb,
    const float* __restrict__ bias, const float* __restrict__ aux,
    void* __restrict__ outv, u16* __restrict__ vt = nullptr)
{
    constexpr int Nn = NJ * 192;
    constexpr int Kp = K + 8;
    __shared__ u16 As[64 * Kp];
    const int tid  = threadIdx.x;
    const int wave = tid >> 6, lane = tid & 63;
    const int quad = lane >> 4, l15 = lane & 15;
    const int m0 = blockIdx.x * 64;

    {
        const u16* src = A + (size_t)m0 * K;
        #pragma unroll
        for (int i = tid; i < 64 * K / 8; i += 256) {
            const int e = i * 8;
            const int r = e / K, c = e - r * K;
            *(short8*)&As[r * Kp + c] = *(const short8*)(src + e);
        }
    }
    __syncthreads();

    #pragma unroll
    for (int j = 0; j < NJ; ++j) {
        const int nb0 = j * 192 + wave * 48;
        const u16* Bbase = Bt + (size_t)(nb0 + l15) * ldb + quad * 8;
        f32x4 acc[4][3] = {};
        #pragma unroll
        for (int ks = 0; ks < K / 32; ++ks) {
            short8 a[4], b[3];
            #pragma unroll
            for (int i = 0; i < 4; ++i)
                a[i] = *(const short8*)&As[(i * 16 + l15) * Kp + ks * 32 + quad * 8];
            #pragma unroll
            for (int t = 0; t < 3; ++t)
                b[t] = *(const short8*)(Bbase + (size_t)t * 16 * ldb + ks * 32);
            #pragma unroll
            for (int i = 0; i < 4; ++i)
                #pragma unroll
                for (int t = 0; t < 3; ++t)
                    acc[i][t] = __builtin_amdgcn_mfma_f32_16x16x32_bf16(
                        a[i], b[t], acc[i][t], 0, 0, 0);
        }
        float bcol[3] = {0.f, 0.f, 0.f};
        {
            #pragma unroll
            for (int t = 0; t < 3; ++t) bcol[t] = bias[nb0 + t * 16 + l15];
        }
        #pragma unroll
        for (int i = 0; i < 4; ++i) {
            #pragma unroll
            for (int reg = 0; reg < 4; ++reg) {
                const int r = m0 + i * 16 + quad * 4 + reg;
                if (MODE == 2) {
                    const int win = r / kN, n = r % kN;
                    const int b = win >> 6, wi = win & 63;
                    const int wh = wi >> 3, ww = wi & 7;
                    const int i1 = n / kWS, j1 = n % kWS;
                    const int h = (wh * kWS + i1 + kSS) % kH;
                    const int w = (ww * kWS + j1 + kSS) % kW;
                    const size_t drow = ((size_t)b * kL + h * kW + w) * kC;
                    #pragma unroll
                    for (int t = 0; t < 3; ++t) {
                        const int c = nb0 + t * 16 + l15;
                        const size_t dest = drow + c;
                        ((float*)outv)[dest] = acc[i][t][reg] + bcol[t] + aux[dest];
                    }
                } else if (MODE == 5 && j == 2) {
                    // scatter v transposed: row win*6*32 + head*32 + d, col n
                    const int win = r / kN, n = r - win * kN;
                    #pragma unroll
                    for (int t = 0; t < 3; ++t) {
                        const int d = nb0 - 384 + t * 16 + l15;
                        const size_t off =
                            ((size_t)win * 192 + d) * 64 + n;  // 192 = 6*32
                        vt[off] = f2bf(acc[i][t][reg] + bcol[t]);
                    }
                } else {
                    #pragma unroll
                    for (int t = 0; t < 3; ++t) {
                        const int c = nb0 + t * 16 + l15;
                        float v = acc[i][t][reg] + bcol[t];
                        ((u16*)outv)[(size_t)r * Nn + c] = f2bf(v);
                    }
                }
            }
        }
    }
}

// ---------------------------------------------------------------------------
// Fused LN2 + MLP: out = x1 + fc2(gelu(fc1(LN(x1)))), one block per 64 tokens.
// v5 = round-1 v1 (measured 238 us, VGPR 120) with ONE change: hidden
// processed in FOUR 192-col chunks -> Hs 50.2->25.6 KB, total LDS 51.2 KB
// -> 3 blocks/CU (was 2), +50% resident waves for the latency-bound phase
// chain. Live register state unchanged (acc1[4][3] + acc2[4][3]).
// Plain __launch_bounds__(256): NO min-occ arg (rounds 2-4: clamps -> spills).
// ---------------------------------------------------------------------------
__global__ __launch_bounds__(256) void mlp_fused(
    float* __restrict__ out,          // holds x1 on entry; final out (RMW)
    const float* __restrict__ gamma, const float* __restrict__ beta,
    const u16* __restrict__ f1_t, const float* __restrict__ fc1_b,
    const u16* __restrict__ f2_t, const float* __restrict__ fc2_b)
{
    constexpr int Kp = 200;   // As row pitch (u16): 192 + 8
    constexpr int Hp = 200;   // Hs row pitch (u16): 192 + 8
    __shared__ u16 As[64 * Kp];   // 25600 B
    __shared__ u16 Hs[64 * Hp];   // 25600 B
    const int tid  = threadIdx.x;
    const int wave = tid >> 6, lane = tid & 63;
    const int quad = lane >> 4, l15 = lane & 15;
    const int m0 = blockIdx.x * 64;

    // ---- LN: 16 lanes/row, 4 rows/wave/round, 4 rounds -> As bf16 ----
    {
        float gv[12], bv[12];
        #pragma unroll
        for (int j = 0; j < 12; ++j) {
            gv[j] = gamma[l15 * 12 + j];
            bv[j] = beta[l15 * 12 + j];
        }
        #pragma unroll
        for (int it = 0; it < 4; ++it) {
            const int r = it * 16 + wave * 4 + quad;
            const float* xp = out + (size_t)(m0 + r) * kC + l15 * 12;
            float4 u0 = *(const float4*)(xp);
            float4 u1 = *(const float4*)(xp + 4);
            float4 u2 = *(const float4*)(xp + 8);
            float v[12] = {u0.x, u0.y, u0.z, u0.w, u1.x, u1.y, u1.z, u1.w,
                           u2.x, u2.y, u2.z, u2.w};
            float s = 0.f, sq = 0.f;
            #pragma unroll
            for (int j = 0; j < 12; ++j) { s += v[j]; sq += v[j] * v[j]; }
            #pragma unroll
            for (int off = 1; off < 16; off <<= 1) {
                s  += __shfl_xor(s, off, 64);
                sq += __shfl_xor(sq, off, 64);
            }
            const float mean = s * (1.0f / kC);
            const float inv  = rsqrtf(sq * (1.0f / kC) - mean * mean + kEps);
            unsigned* ap = (unsigned*)&As[r * Kp + l15 * 12];
            #pragma unroll
            for (int j = 0; j < 6; ++j) {
                float a0 = (v[2 * j]     - mean) * inv * gv[2 * j]     + bv[2 * j];
                float a1 = (v[2 * j + 1] - mean) * inv * gv[2 * j + 1] + bv[2 * j + 1];
                ap[j] = (unsigned)f2bf(a0) | ((unsigned)f2bf(a1) << 16);
            }
        }
    }
    __syncthreads();

    f32x4 acc2[4][3] = {};   // fc2 accumulator, persists across chunks
    for (int c = 0; c < 4; ++c) {
        // ---- fc1: rows 0..63 x hidden cols [c*192 + wave*48, +48) ----
        f32x4 acc1[4][3] = {};
        {
            const u16* B1 = f1_t + (size_t)(c * 192 + wave * 48 + l15) * 192 + quad * 8;
            #pragma unroll
            for (int ks = 0; ks < 6; ++ks) {
                short8 a[4], b[3];
                #pragma unroll
                for (int i = 0; i < 4; ++i)
                    a[i] = *(const short8*)&As[(i * 16 + l15) * Kp + ks * 32 + quad * 8];
                #pragma unroll
                for (int t = 0; t < 3; ++t)
                    b[t] = *(const short8*)(B1 + (size_t)t * 16 * 192 + ks * 32);
                #pragma unroll
                for (int i = 0; i < 4; ++i)
                    #pragma unroll
                    for (int t = 0; t < 3; ++t)
                        acc1[i][t] = __builtin_amdgcn_mfma_f32_16x16x32_bf16(
                            a[i], b[t], acc1[i][t], 0, 0, 0);
            }
        }
        __syncthreads();   // c>0: all waves done reading Hs chunk c-1
        // ---- bias + GELU -> Hs (bf16) ----
        #pragma unroll
        for (int t = 0; t < 3; ++t) {
            const int cc = wave * 48 + t * 16 + l15;
            const float bb = fc1_b[c * 192 + cc];
            #pragma unroll
            for (int i = 0; i < 4; ++i) {
                #pragma unroll
                for (int reg = 0; reg < 4; ++reg) {
                    const int r = i * 16 + quad * 4 + reg;
                    Hs[r * Hp + cc] = f2bf(gelu_f(acc1[i][t][reg] + bb));
                }
            }
        }
        __syncthreads();
        // ---- fc2: rows 0..63 x out cols [wave*48,+48), K=192 from Hs ----
        {
            const u16* B2 = f2_t + (size_t)(wave * 48 + l15) * 768 + c * 192 + quad * 8;
            #pragma unroll
            for (int ks = 0; ks < 6; ++ks) {
                short8 a[4], b[3];
                #pragma unroll
                for (int i = 0; i < 4; ++i)
                    a[i] = *(const short8*)&Hs[(i * 16 + l15) * Hp + ks * 32 + quad * 8];
                #pragma unroll
                for (int t = 0; t < 3; ++t)
                    b[t] = *(const short8*)(B2 + (size_t)t * 16 * 768 + ks * 32);
                #pragma unroll
                for (int i = 0; i < 4; ++i)
                    #pragma unroll
                    for (int t = 0; t < 3; ++t)
                        acc2[i][t] = __builtin_amdgcn_mfma_f32_16x16x32_bf16(
                            a[i], b[t], acc2[i][t], 0, 0, 0);
            }
        }
    }
    // ---- epilogue: out = x1 + acc2 + fc2_b ----
    #pragma unroll
    for (int t = 0; t < 3; ++t) {
        const int cc = wave * 48 + t * 16 + l15;
        const float bb = fc2_b[cc];
        #pragma unroll
        for (int i = 0; i < 4; ++i) {
            #pragma unroll
            for (int reg = 0; reg < 4; ++reg) {
                const int r = m0 + i * 16 + quad * 4 + reg;
                float* p = out + (size_t)r * kC + cc;
                *p = acc2[i][t][reg] + bb + *p;
            }
        }
    }
}

// ---------------------------------------------------------------------------
// MFMA window attention v2: ONE WAVE per (window, head).
// ---------------------------------------------------------------------------
__global__ __launch_bounds__(256) void attn_mfma(
    const u16* __restrict__ qkv, const u16* __restrict__ vt,
    const float* __restrict__ T, u16* __restrict__ out)
{
    __shared__ u16 Ps[4][64][72];
    const int tid = threadIdx.x;
    const int wave = tid >> 6, lane = tid & 63;
    const int quad = lane >> 4, l15 = lane & 15;
    const int pair = blockIdx.x * 4 + wave;
    const int win = pair / 6, head = pair - win * 6;
    const int wi = win & 63;
    const int cls = (((wi >> 3) == 7) ? 2 : 0) + (((wi & 7) == 7) ? 1 : 0);
    const float* Tb = T + (size_t)(cls * 6 + head) * 49 * 49;

    const u16* base = qkv + (size_t)win * 49 * 576 + head * 32 + quad * 8;
    short8 zz = {};
    short8 qa[4], kb[4];
    #pragma unroll
    for (int i = 0; i < 4; ++i) {
        const int n = i * 16 + l15;
        qa[i] = (n < 49) ? *(const short8*)(base + (size_t)n * 576) : zz;
        kb[i] = (n < 49) ? *(const short8*)(base + (size_t)n * 576 + 192) : zz;
    }
    f32x4 acc[4][4];
    #pragma unroll
    for (int i = 0; i < 4; ++i) {
        #pragma unroll
        for (int reg = 0; reg < 4; ++reg) {
            const int n = i * 16 + quad * 4 + reg;
            const bool nv = (n < 49);
            const float* Trow = Tb + (nv ? n : 0) * 49;
            #pragma unroll
            for (int j = 0; j < 3; ++j)
                acc[i][j][reg] = nv ? Trow[j * 16 + l15] : 0.f;
            acc[i][3][reg] = (nv && l15 == 0) ? Trow[48] : -30000.f;
        }
    }
    #pragma unroll
    for (int i = 0; i < 4; ++i)
        #pragma unroll
        for (int j = 0; j < 4; ++j)
            acc[i][j] = __builtin_amdgcn_mfma_f32_16x16x32_bf16(
                qa[i], kb[j], acc[i][j], 0, 0, 0);
    float rowinv[4][4];
    #pragma unroll
    for (int i = 0; i < 4; ++i) {
        #pragma unroll
        for (int reg = 0; reg < 4; ++reg) {
            const int n = i * 16 + quad * 4 + reg;
            float e0 = __expf(acc[i][0][reg]), e1 = __expf(acc[i][1][reg]);
            float e2 = __expf(acc[i][2][reg]), e3 = __expf(acc[i][3][reg]);
            float sum = e0 + e1 + e2 + e3;
            #pragma unroll
            for (int off = 1; off < 16; off <<= 1)
                sum += __shfl_xor(sum, off, 64);
            rowinv[i][reg] = 1.0f / sum;
            Ps[wave][n][0 * 16 + l15] = f2bf(e0);
            Ps[wave][n][1 * 16 + l15] = f2bf(e1);
            Ps[wave][n][2 * 16 + l15] = f2bf(e2);
            Ps[wave][n][3 * 16 + l15] = f2bf(e3);
        }
    }
    const u16* vb_base = vt + ((size_t)pair * 32 + l15) * 64 + quad * 8;
    f32x4 o[4][2] = {};
    #pragma unroll
    for (int ks = 0; ks < 2; ++ks) {
        short8 pa[4], vb[2];
        #pragma unroll
        for (int i = 0; i < 4; ++i)
            pa[i] = *(const short8*)&Ps[wave][i * 16 + l15][ks * 32 + quad * 8];
        #pragma unroll
        for (int t = 0; t < 2; ++t)
            vb[t] = *(const short8*)(vb_base + (size_t)t * 16 * 64 + ks * 32);
        #pragma unroll
        for (int i = 0; i < 4; ++i)
            #pragma unroll
            for (int t = 0; t < 2; ++t)
                o[i][t] = __builtin_amdgcn_mfma_f32_16x16x32_bf16(
                    pa[i], vb[t], o[i][t], 0, 0, 0);
    }
    u16* obase = out + (size_t)win * 49 * 192 + head * 32;
    #pragma unroll
    for (int i = 0; i < 4; ++i) {
        #pragma unroll
        for (int reg = 0; reg < 4; ++reg) {
            const int n = i * 16 + quad * 4 + reg;
            if (n < 49) {
                const float inv = rowinv[i][reg];
                obase[(size_t)n * 192 + l15]      = f2bf(o[i][0][reg] * inv);
                obase[(size_t)n * 192 + 16 + l15] = f2bf(o[i][1][reg] * inv);
            }
        }
    }
}

// ---------------------------------------------------------------------------
extern "C" void kernel_launch(void* const* d_in, const int* in_sizes, int n_in,
                              void* d_out, int out_size, void* d_ws, size_t ws_size,
                              hipStream_t stream)
{
    const float* x      = (const float*)d_in[0];
    const float* gamma1 = (const float*)d_in[1];
    const float* beta1  = (const float*)d_in[2];
    const float* qkv_w  = (const float*)d_in[3];
    const float* qkv_b  = (const float*)d_in[4];
    const float* proj_w = (const float*)d_in[5];
    const float* proj_b = (const float*)d_in[6];
    const float* btab   = (const float*)d_in[7];
    const float* gamma2 = (const float*)d_in[8];
    const float* beta2  = (const float*)d_in[9];
    const float* fc1_w  = (const float*)d_in[10];
    const float* fc1_b  = (const float*)d_in[11];
    const float* fc2_w  = (const float*)d_in[12];
    const float* fc2_b  = (const float*)d_in[13];
    float* out = (float*)d_out;

    // ws budget EXACTLY kTok*768*2 B. d_out (77 MB fp32) doubles as scratch
    // until the proj epilogue: qkv_t | bm_tab | qkv_bs | vT(50.3 MB).
    u16* buf_a = (u16*)d_ws;                      // kTok*192 bf16
    u16* buf_b = buf_a + (size_t)kTok * 192;      // kTok*576 bf16 (q,k used)
    u16* qkv_t = (u16*)d_out;                     // 110592 u16
    float* bm_tab = (float*)d_out + 55296;        // 57624 f32
    float* qkv_bs = bm_tab + 57624;               // 576 f32
    u16* vT = (u16*)d_out + 230400;               // 2048*6*32*64 u16, 16B-aligned
    u16* wt2   = (u16*)d_ws + (size_t)kTok * 768 - 331776;
    u16* proj_t = wt2;
    u16* f1_t   = wt2 + 36864;
    u16* f2_t   = f1_t + 147456;

    // 0) prep: qkv weights (q pre-scaled), bias+mask table, scaled qkv bias
    wprep_qkv<<<(110592 + 255) / 256, 256, 0, stream>>>(qkv_w, qkv_t);
    prep_bm<<<(57624 + 255) / 256, 256, 0, stream>>>(btab, qkv_b, bm_tab, qkv_bs);
    // 1) LN1 + cyclic shift + window partition
    ln_kernel<<<kTok / 4, 256, 0, stream>>>(x, gamma1, beta1, buf_a, 1);
    // 2) qkv GEMM -> q,k rows in buf_b; v scattered transposed into vT
    gemm_mfma<5, 192, 3><<<kTok / 64, 256, 0, stream>>>(
        buf_a, qkv_t, 192, qkv_bs, nullptr, buf_b, vT);
    // 3) MFMA window attention -> buf_a (bf16)
    attn_mfma<<<(kNWin * kNH) / 4, 256, 0, stream>>>(buf_b, vT, bm_tab, buf_a);
    // 4) remaining weight prep into buf_b tail (qkv dead now)
    wprep_rest<<<(331776 + 255) / 256, 256, 0, stream>>>(
        proj_w, fc1_w, fc2_w, proj_t, f1_t, f2_t);
    // 5) proj GEMM + window reverse + unshift + residual(x) -> x1 in d_out
    gemm_mfma<2, 192, 1><<<kTok / 64, 256, 0, stream>>>(
        buf_a, proj_t, 192, proj_b, x, out);
    // 6) fused LN2 + fc1 + GELU + fc2 + residual, hidden in 4 LDS chunks
    mlp_fused<<<kTok / 64, 256, 0, stream>>>(
        out, gamma2, beta2, f1_t, fc1_b, f2_t, fc2_b);
}

// Round 6
// 498.119 us; speedup vs baseline: 1.4157x; 1.0620x over previous
//
#include <hip/hip_runtime.h>
#include <math.h>

namespace {
constexpr int kBatch = 32, kH = 56, kW = 56, kC = 192, kNH = 6, kWS = 7, kSS = 3;
constexpr int kL   = kH * kW;        // 3136
constexpr int kN   = kWS * kWS;      // 49
constexpr int kTok = kBatch * kL;    // 100352
constexpr int kNWin = kTok / kN;     // 2048 windows
constexpr float kEps   = 1e-3f;
constexpr float kScale = 0.17677669529663687f;  // HD^-0.5
}

typedef unsigned short u16;
typedef __attribute__((ext_vector_type(8))) short short8;   // 8 x bf16 (4 VGPRs)
typedef __attribute__((ext_vector_type(4))) float f32x4;    // MFMA accumulator

__device__ __forceinline__ float bf2f(u16 u) {
    return __uint_as_float(((unsigned int)u) << 16);
}
__device__ __forceinline__ u16 f2bf(float f) {  // round-to-nearest-even
    unsigned int x = __float_as_uint(f);
    return (u16)((x + 0x7FFFu + ((x >> 16) & 1u)) >> 16);
}
// tanh-approx GELU. |err vs exact erf-GELU| < 5e-4 everywhere; bf16 output
// rounding dominates. HW v_exp_f32 instead of libm erff.
__device__ __forceinline__ float gelu_f(float x) {
    float z = 0.7978845608028654f * x * (1.0f + 0.044715f * x * x);
    float t = 1.0f - 2.0f / (1.0f + __expf(2.0f * z));
    return 0.5f * x * (1.0f + t);
}

// ---------------------------------------------------------------------------
// LayerNorm over C=192 (fp32 in, bf16 out), one wave per token. (LN1 only.)
// ---------------------------------------------------------------------------
__global__ __launch_bounds__(256) void ln_kernel(
    const float* __restrict__ x, const float* __restrict__ gamma,
    const float* __restrict__ beta, u16* __restrict__ out, int do_shift)
{
    const int wave = threadIdx.x >> 6;
    const int lane = threadIdx.x & 63;
    const int tok = (blockIdx.x << 2) + wave;
    const float* xp = x + (size_t)tok * kC;
    float v0 = xp[lane], v1 = xp[lane + 64], v2 = xp[lane + 128];
    float s  = v0 + v1 + v2;
    float sq = v0 * v0 + v1 * v1 + v2 * v2;
    #pragma unroll
    for (int off = 32; off > 0; off >>= 1) {
        s  += __shfl_down(s, off, 64);
        sq += __shfl_down(sq, off, 64);
    }
    s  = __shfl(s, 0, 64);
    sq = __shfl(sq, 0, 64);
    const float mean = s * (1.0f / kC);
    const float var  = sq * (1.0f / kC) - mean * mean;
    const float inv  = rsqrtf(var + kEps);
    size_t orow;
    if (do_shift) {
        const int b = tok / kL, hw = tok % kL;
        const int h = hw / kW, w = hw % kW;
        const int hs = (h + kH - kSS) % kH;
        const int ws = (w + kW - kSS) % kW;
        const int wh = hs / kWS, ii = hs % kWS;
        const int ww = ws / kWS, jj = ws % kWS;
        orow = (size_t)(b * 64 + wh * 8 + ww) * kN + (ii * kWS + jj);
    } else {
        orow = tok;
    }
    u16* op = out + orow * kC;
    op[lane]       = f2bf((v0 - mean) * inv * gamma[lane]       + beta[lane]);
    op[lane + 64]  = f2bf((v1 - mean) * inv * gamma[lane + 64]  + beta[lane + 64]);
    op[lane + 128] = f2bf((v2 - mean) * inv * gamma[lane + 128] + beta[lane + 128]);
}

// ---------------------------------------------------------------------------
// Weight prep. qkv: fp32 (192 x 576) -> bf16 n-major (576 x 192), q-cols
// pre-scaled by kScale.
// ---------------------------------------------------------------------------
__global__ __launch_bounds__(256) void wprep_qkv(
    const float* __restrict__ w, u16* __restrict__ wt)
{
    const int idx = blockIdx.x * 256 + threadIdx.x;
    if (idx >= 576 * 192) return;
    const int n = idx / 192, k = idx - n * 192;
    float v = w[(size_t)k * 576 + n];
    if (n < 192) v *= kScale;
    wt[idx] = f2bf(v);
}

// wprep_rest v2: + 4th segment writing rowmap (window row -> spatial token),
// used by proj_mlp_fused for the residual gather / output scatter.
__global__ __launch_bounds__(256) void wprep_rest(
    const float* __restrict__ pw, const float* __restrict__ f1w,
    const float* __restrict__ f2w, u16* __restrict__ proj_t,
    u16* __restrict__ f1_t, u16* __restrict__ f2_t, int* __restrict__ rowmap)
{
    int idx = blockIdx.x * 256 + threadIdx.x;
    if (idx < 36864) {
        const int n = idx / 192, k = idx - n * 192;
        proj_t[idx] = f2bf(pw[(size_t)k * 192 + n]);
        return;
    }
    idx -= 36864;
    if (idx < 147456) {
        const int n = idx / 192, k = idx - n * 192;
        f1_t[idx] = f2bf(f1w[(size_t)k * 768 + n]);
        return;
    }
    idx -= 147456;
    if (idx < 147456) {
        const int n = idx / 768, k = idx - n * 768;
        f2_t[idx] = f2bf(f2w[(size_t)k * 192 + n]);
        return;
    }
    idx -= 147456;
    if (idx < kTok) {
        const int win = idx / kN, n = idx - win * kN;
        const int b = win >> 6, wi = win & 63;
        const int wh = wi >> 3, ww = wi & 7;
        const int i1 = n / kWS, j1 = n - i1 * kWS;
        const int h = (wh * kWS + i1 + kSS) % kH;
        const int w = (ww * kWS + j1 + kSS) % kW;
        rowmap[idx] = b * kL + h * kW + w;
    }
}

// ---------------------------------------------------------------------------
// Bias+mask table T[cls][head][n][m] (mask folded, used as MFMA C-init) and
// scaled qkv bias copy (q-part * kScale).
// ---------------------------------------------------------------------------
__global__ __launch_bounds__(256) void prep_bm(
    const float* __restrict__ btab, const float* __restrict__ qkv_b,
    float* __restrict__ T, float* __restrict__ qkv_bs)
{
    const int idx = blockIdx.x * 256 + threadIdx.x;
    if (idx < 576) qkv_bs[idx] = (idx < 192) ? qkv_b[idx] * kScale : qkv_b[idx];
    if (idx >= 4 * 6 * 49 * 49) return;
    const int m = idx % 49, n = (idx / 49) % 49;
    const int head = (idx / 2401) % 6, cls = idx / (2401 * 6);
    const int i1 = n / 7, j1 = n % 7, i2 = m / 7, j2 = m % 7;
    float v = btab[((i1 - i2 + 6) * 13 + (j1 - j2 + 6)) * kNH + head];
    const int whE = cls >> 1, wwE = cls & 1;
    const int r1 = (whE ? (i1 < 4 ? 1 : 2) : 0) * 3 + (wwE ? (j1 < 4 ? 1 : 2) : 0);
    const int r2 = (whE ? (i2 < 4 ? 1 : 2) : 0) * 3 + (wwE ? (j2 < 4 ? 1 : 2) : 0);
    if (r1 != r2) v -= 100.f;
    T[idx] = v;
}

// ---------------------------------------------------------------------------
// MFMA GEMM with LDS-staged A: out(M x Nn) = A_bf16(M x K) @ Bt + bias.
// MODE 0: bf16 out
// MODE 5 (qkv): j<2 -> bf16 q,k into rows of 576; j==2 -> scatter v
//               TRANSPOSED into vt[(win*6+head)*32 + d][64] (aux2).
// NOTE: plain __launch_bounds__(256) ONLY (rounds 2-4: min-occ arg clamps
// VGPR below live state -> ~1 GB spill traffic).
// ---------------------------------------------------------------------------
template <int MODE, int K, int NJ>
__global__ __launch_bounds__(256) void gemm_mfma(
    const u16* __restrict__ A, const u16* __restrict__ Bt, int ldb,
    const float* __restrict__ bias, const float* __restrict__ aux,
    void* __restrict__ outv, u16* __restrict__ vt = nullptr)
{
    constexpr int Nn = NJ * 192;
    constexpr int Kp = K + 8;
    __shared__ u16 As[64 * Kp];
    const int tid  = threadIdx.x;
    const int wave = tid >> 6, lane = tid & 63;
    const int quad = lane >> 4, l15 = lane & 15;
    const int m0 = blockIdx.x * 64;

    {
        const u16* src = A + (size_t)m0 * K;
        #pragma unroll
        for (int i = tid; i < 64 * K / 8; i += 256) {
            const int e = i * 8;
            const int r = e / K, c = e - r * K;
            *(short8*)&As[r * Kp + c] = *(const short8*)(src + e);
        }
    }
    __syncthreads();

    #pragma unroll
    for (int j = 0; j < NJ; ++j) {
        const int nb0 = j * 192 + wave * 48;
        const u16* Bbase = Bt + (size_t)(nb0 + l15) * ldb + quad * 8;
        f32x4 acc[4][3] = {};
        #pragma unroll
        for (int ks = 0; ks < K / 32; ++ks) {
            short8 a[4], b[3];
            #pragma unroll
            for (int i = 0; i < 4; ++i)
                a[i] = *(const short8*)&As[(i * 16 + l15) * Kp + ks * 32 + quad * 8];
            #pragma unroll
            for (int t = 0; t < 3; ++t)
                b[t] = *(const short8*)(Bbase + (size_t)t * 16 * ldb + ks * 32);
            #pragma unroll
            for (int i = 0; i < 4; ++i)
                #pragma unroll
                for (int t = 0; t < 3; ++t)
                    acc[i][t] = __builtin_amdgcn_mfma_f32_16x16x32_bf16(
                        a[i], b[t], acc[i][t], 0, 0, 0);
        }
        float bcol[3] = {0.f, 0.f, 0.f};
        {
            #pragma unroll
            for (int t = 0; t < 3; ++t) bcol[t] = bias[nb0 + t * 16 + l15];
        }
        #pragma unroll
        for (int i = 0; i < 4; ++i) {
            #pragma unroll
            for (int reg = 0; reg < 4; ++reg) {
                const int r = m0 + i * 16 + quad * 4 + reg;
                if (MODE == 5 && j == 2) {
                    // scatter v transposed: row win*6*32 + head*32 + d, col n
                    const int win = r / kN, n = r - win * kN;
                    #pragma unroll
                    for (int t = 0; t < 3; ++t) {
                        const int d = nb0 - 384 + t * 16 + l15;
                        const size_t off =
                            ((size_t)win * 192 + d) * 64 + n;  // 192 = 6*32
                        vt[off] = f2bf(acc[i][t][reg] + bcol[t]);
                    }
                } else {
                    #pragma unroll
                    for (int t = 0; t < 3; ++t) {
                        const int c = nb0 + t * 16 + l15;
                        float v = acc[i][t][reg] + bcol[t];
                        ((u16*)outv)[(size_t)r * Nn + c] = f2bf(v);
                    }
                }
            }
        }
    }
}

// ---------------------------------------------------------------------------
// MEGA: proj GEMM + residual gather + LN2 + MLP + scatter, one block/64 rows.
//   x1 = x[spatial] + attnout @ proj_w + proj_b      (48 f32 REGS, no HBM)
//   out[spatial]   = x1 + fc2(gelu(fc1(LN(x1))))
// Removes the proj kernel, the x1 write+read round-trip (~143 MB), one
// launch, and one A-tile re-stage. LN2 done with cross-wave LDS reduction
// staged in the Hs region (dead until first gelu write). MLP = the proven
// v5 4-chunk loop. LDS 51.5 KB. Unified-RF limits us to 2 waves/SIMD
// regardless (round-5 finding), so the extra register state (x1) is free.
// ---------------------------------------------------------------------------
__global__ __launch_bounds__(256) void proj_mlp_fused(
    const u16* __restrict__ A,        // attn out (window-ordered rows, bf16)
    const u16* __restrict__ proj_t, const float* __restrict__ proj_b,
    const float* __restrict__ x,      // residual-1 source (spatial order)
    const int* __restrict__ rowmap,   // window row -> spatial token
    const float* __restrict__ gamma, const float* __restrict__ beta,
    const u16* __restrict__ f1_t, const float* __restrict__ fc1_b,
    const u16* __restrict__ f2_t, const float* __restrict__ fc2_b,
    float* __restrict__ out)
{
    constexpr int Kp = 200;   // As row pitch (u16)
    constexpr int Hp = 200;   // Hs row pitch (u16)
    __shared__ u16 As[64 * Kp];   // 25600 B: attn-out tile, then LN2 output
    __shared__ u16 Hs[64 * Hp];   // 25600 B: LN stats overlay, then hidden
    __shared__ int rowdest[64];
    const int tid  = threadIdx.x;
    const int wave = tid >> 6, lane = tid & 63;
    const int quad = lane >> 4, l15 = lane & 15;
    const int m0 = blockIdx.x * 64;
    float* Hsf = (float*)Hs;      // stats overlay (first 2560 B)

    // ---- stage attn-out tile + rowdest ----
    {
        const u16* src = A + (size_t)m0 * 192;
        #pragma unroll
        for (int i = tid; i < 64 * 192 / 8; i += 256) {
            const int e = i * 8;
            const int r = e / 192, c = e - r * 192;
            *(short8*)&As[r * Kp + c] = *(const short8*)(src + e);
        }
        if (tid < 64) rowdest[tid] = rowmap[m0 + tid];
    }
    __syncthreads();

    // ---- residual gather (issued early; latency hides under proj GEMM) ----
    float x1[4][3][4];
    #pragma unroll
    for (int i = 0; i < 4; ++i) {
        #pragma unroll
        for (int reg = 0; reg < 4; ++reg) {
            const float* xr = x + (size_t)rowdest[i * 16 + quad * 4 + reg] * kC
                              + wave * 48 + l15;
            #pragma unroll
            for (int t = 0; t < 3; ++t) x1[i][t][reg] = xr[t * 16];
        }
    }

    // ---- proj GEMM: acc = As @ proj_t (cols wave*48..+48), K=192 ----
    f32x4 acc[4][3] = {};
    {
        const u16* Bbase = proj_t + (size_t)(wave * 48 + l15) * 192 + quad * 8;
        #pragma unroll
        for (int ks = 0; ks < 6; ++ks) {
            short8 a[4], b[3];
            #pragma unroll
            for (int i = 0; i < 4; ++i)
                a[i] = *(const short8*)&As[(i * 16 + l15) * Kp + ks * 32 + quad * 8];
            #pragma unroll
            for (int t = 0; t < 3; ++t)
                b[t] = *(const short8*)(Bbase + (size_t)t * 16 * 192 + ks * 32);
            #pragma unroll
            for (int i = 0; i < 4; ++i)
                #pragma unroll
                for (int t = 0; t < 3; ++t)
                    acc[i][t] = __builtin_amdgcn_mfma_f32_16x16x32_bf16(
                        a[i], b[t], acc[i][t], 0, 0, 0);
        }
    }
    // ---- x1 = x + proj + bias (registers only) ----
    {
        float bcol[3];
        #pragma unroll
        for (int t = 0; t < 3; ++t) bcol[t] = proj_b[wave * 48 + t * 16 + l15];
        #pragma unroll
        for (int i = 0; i < 4; ++i)
            #pragma unroll
            for (int t = 0; t < 3; ++t)
                #pragma unroll
                for (int reg = 0; reg < 4; ++reg)
                    x1[i][t][reg] += acc[i][t][reg] + bcol[t];
    }

    // ---- LN2 partials: sum over this wave's 48 cols per row -> Hs stats ----
    #pragma unroll
    for (int i = 0; i < 4; ++i) {
        #pragma unroll
        for (int reg = 0; reg < 4; ++reg) {
            float s  = x1[i][0][reg] + x1[i][1][reg] + x1[i][2][reg];
            float sq = x1[i][0][reg] * x1[i][0][reg]
                     + x1[i][1][reg] * x1[i][1][reg]
                     + x1[i][2][reg] * x1[i][2][reg];
            #pragma unroll
            for (int off = 1; off < 16; off <<= 1) {
                s  += __shfl_xor(s, off, 64);
                sq += __shfl_xor(sq, off, 64);
            }
            if (l15 == 0) {
                const int r = i * 16 + quad * 4 + reg;
                Hsf[r * 8 + wave * 2]     = s;
                Hsf[r * 8 + wave * 2 + 1] = sq;
            }
        }
    }
    __syncthreads();   // also: all As GEMM reads complete
    if (tid < 64) {
        const float s  = Hsf[tid * 8] + Hsf[tid * 8 + 2] + Hsf[tid * 8 + 4] + Hsf[tid * 8 + 6];
        const float sq = Hsf[tid * 8 + 1] + Hsf[tid * 8 + 3] + Hsf[tid * 8 + 5] + Hsf[tid * 8 + 7];
        const float mean = s * (1.0f / kC);
        const float inv  = rsqrtf(sq * (1.0f / kC) - mean * mean + kEps);
        Hsf[512 + tid * 2]     = mean;
        Hsf[512 + tid * 2 + 1] = inv;
    }
    __syncthreads();
    // ---- LN2 output -> As (bf16) ----
    {
        float gv[3], bv[3];
        #pragma unroll
        for (int t = 0; t < 3; ++t) {
            gv[t] = gamma[wave * 48 + t * 16 + l15];
            bv[t] = beta[wave * 48 + t * 16 + l15];
        }
        #pragma unroll
        for (int i = 0; i < 4; ++i) {
            #pragma unroll
            for (int reg = 0; reg < 4; ++reg) {
                const int r = i * 16 + quad * 4 + reg;
                const float mean = Hsf[512 + r * 2];
                const float inv  = Hsf[513 + r * 2];
                #pragma unroll
                for (int t = 0; t < 3; ++t)
                    As[r * Kp + wave * 48 + t * 16 + l15] =
                        f2bf((x1[i][t][reg] - mean) * inv * gv[t] + bv[t]);
            }
        }
    }
    __syncthreads();

    // ---- MLP: 4 chunks of 192 hidden cols (v5-proven loop) ----
    f32x4 acc2[4][3] = {};
    for (int c = 0; c < 4; ++c) {
        f32x4 acc1[4][3] = {};
        {
            const u16* B1 = f1_t + (size_t)(c * 192 + wave * 48 + l15) * 192 + quad * 8;
            #pragma unroll
            for (int ks = 0; ks < 6; ++ks) {
                short8 a[4], b[3];
                #pragma unroll
                for (int i = 0; i < 4; ++i)
                    a[i] = *(const short8*)&As[(i * 16 + l15) * Kp + ks * 32 + quad * 8];
                #pragma unroll
                for (int t = 0; t < 3; ++t)
                    b[t] = *(const short8*)(B1 + (size_t)t * 16 * 192 + ks * 32);
                #pragma unroll
                for (int i = 0; i < 4; ++i)
                    #pragma unroll
                    for (int t = 0; t < 3; ++t)
                        acc1[i][t] = __builtin_amdgcn_mfma_f32_16x16x32_bf16(
                            a[i], b[t], acc1[i][t], 0, 0, 0);
            }
        }
        __syncthreads();   // c>0: all waves done reading Hs chunk c-1
        #pragma unroll
        for (int t = 0; t < 3; ++t) {
            const int cc = wave * 48 + t * 16 + l15;
            const float bb = fc1_b[c * 192 + cc];
            #pragma unroll
            for (int i = 0; i < 4; ++i) {
                #pragma unroll
                for (int reg = 0; reg < 4; ++reg) {
                    const int r = i * 16 + quad * 4 + reg;
                    Hs[r * Hp + cc] = f2bf(gelu_f(acc1[i][t][reg] + bb));
                }
            }
        }
        __syncthreads();
        {
            const u16* B2 = f2_t + (size_t)(wave * 48 + l15) * 768 + c * 192 + quad * 8;
            #pragma unroll
            for (int ks = 0; ks < 6; ++ks) {
                short8 a[4], b[3];
                #pragma unroll
                for (int i = 0; i < 4; ++i)
                    a[i] = *(const short8*)&Hs[(i * 16 + l15) * Hp + ks * 32 + quad * 8];
                #pragma unroll
                for (int t = 0; t < 3; ++t)
                    b[t] = *(const short8*)(B2 + (size_t)t * 16 * 768 + ks * 32);
                #pragma unroll
                for (int i = 0; i < 4; ++i)
                    #pragma unroll
                    for (int t = 0; t < 3; ++t)
                        acc2[i][t] = __builtin_amdgcn_mfma_f32_16x16x32_bf16(
                            a[i], b[t], acc2[i][t], 0, 0, 0);
            }
        }
    }
    // ---- epilogue: out[spatial] = x1 + acc2 + fc2_b ----
    #pragma unroll
    for (int t = 0; t < 3; ++t) {
        const int cc = wave * 48 + t * 16 + l15;
        const float bb = fc2_b[cc];
        #pragma unroll
        for (int i = 0; i < 4; ++i) {
            #pragma unroll
            for (int reg = 0; reg < 4; ++reg) {
                const int dr = rowdest[i * 16 + quad * 4 + reg];
                out[(size_t)dr * kC + cc] = x1[i][t][reg] + acc2[i][t][reg] + bb;
            }
        }
    }
}

// ---------------------------------------------------------------------------
// MFMA window attention v2: ONE WAVE per (window, head).
// ---------------------------------------------------------------------------
__global__ __launch_bounds__(256) void attn_mfma(
    const u16* __restrict__ qkv, const u16* __restrict__ vt,
    const float* __restrict__ T, u16* __restrict__ out)
{
    __shared__ u16 Ps[4][64][72];
    const int tid = threadIdx.x;
    const int wave = tid >> 6, lane = tid & 63;
    const int quad = lane >> 4, l15 = lane & 15;
    const int pair = blockIdx.x * 4 + wave;
    const int win = pair / 6, head = pair - win * 6;
    const int wi = win & 63;
    const int cls = (((wi >> 3) == 7) ? 2 : 0) + (((wi & 7) == 7) ? 1 : 0);
    const float* Tb = T + (size_t)(cls * 6 + head) * 49 * 49;

    const u16* base = qkv + (size_t)win * 49 * 576 + head * 32 + quad * 8;
    short8 zz = {};
    short8 qa[4], kb[4];
    #pragma unroll
    for (int i = 0; i < 4; ++i) {
        const int n = i * 16 + l15;
        qa[i] = (n < 49) ? *(const short8*)(base + (size_t)n * 576) : zz;
        kb[i] = (n < 49) ? *(const short8*)(base + (size_t)n * 576 + 192) : zz;
    }
    f32x4 acc[4][4];
    #pragma unroll
    for (int i = 0; i < 4; ++i) {
        #pragma unroll
        for (int reg = 0; reg < 4; ++reg) {
            const int n = i * 16 + quad * 4 + reg;
            const bool nv = (n < 49);
            const float* Trow = Tb + (nv ? n : 0) * 49;
            #pragma unroll
            for (int j = 0; j < 3; ++j)
                acc[i][j][reg] = nv ? Trow[j * 16 + l15] : 0.f;
            acc[i][3][reg] = (nv && l15 == 0) ? Trow[48] : -30000.f;
        }
    }
    #pragma unroll
    for (int i = 0; i < 4; ++i)
        #pragma unroll
        for (int j = 0; j < 4; ++j)
            acc[i][j] = __builtin_amdgcn_mfma_f32_16x16x32_bf16(
                qa[i], kb[j], acc[i][j], 0, 0, 0);
    float rowinv[4][4];
    #pragma unroll
    for (int i = 0; i < 4; ++i) {
        #pragma unroll
        for (int reg = 0; reg < 4; ++reg) {
            const int n = i * 16 + quad * 4 + reg;
            float e0 = __expf(acc[i][0][reg]), e1 = __expf(acc[i][1][reg]);
            float e2 = __expf(acc[i][2][reg]), e3 = __expf(acc[i][3][reg]);
            float sum = e0 + e1 + e2 + e3;
            #pragma unroll
            for (int off = 1; off < 16; off <<= 1)
                sum += __shfl_xor(sum, off, 64);
            rowinv[i][reg] = 1.0f / sum;
            Ps[wave][n][0 * 16 + l15] = f2bf(e0);
            Ps[wave][n][1 * 16 + l15] = f2bf(e1);
            Ps[wave][n][2 * 16 + l15] = f2bf(e2);
            Ps[wave][n][3 * 16 + l15] = f2bf(e3);
        }
    }
    const u16* vb_base = vt + ((size_t)pair * 32 + l15) * 64 + quad * 8;
    f32x4 o[4][2] = {};
    #pragma unroll
    for (int ks = 0; ks < 2; ++ks) {
        short8 pa[4], vb[2];
        #pragma unroll
        for (int i = 0; i < 4; ++i)
            pa[i] = *(const short8*)&Ps[wave][i * 16 + l15][ks * 32 + quad * 8];
        #pragma unroll
        for (int t = 0; t < 2; ++t)
            vb[t] = *(const short8*)(vb_base + (size_t)t * 16 * 64 + ks * 32);
        #pragma unroll
        for (int i = 0; i < 4; ++i)
            #pragma unroll
            for (int t = 0; t < 2; ++t)
                o[i][t] = __builtin_amdgcn_mfma_f32_16x16x32_bf16(
                    pa[i], vb[t], o[i][t], 0, 0, 0);
    }
    u16* obase = out + (size_t)win * 49 * 192 + head * 32;
    #pragma unroll
    for (int i = 0; i < 4; ++i) {
        #pragma unroll
        for (int reg = 0; reg < 4; ++reg) {
            const int n = i * 16 + quad * 4 + reg;
            if (n < 49) {
                const float inv = rowinv[i][reg];
                obase[(size_t)n * 192 + l15]      = f2bf(o[i][0][reg] * inv);
                obase[(size_t)n * 192 + 16 + l15] = f2bf(o[i][1][reg] * inv);
            }
        }
    }
}

// ---------------------------------------------------------------------------
extern "C" void kernel_launch(void* const* d_in, const int* in_sizes, int n_in,
                              void* d_out, int out_size, void* d_ws, size_t ws_size,
                              hipStream_t stream)
{
    const float* x      = (const float*)d_in[0];
    const float* gamma1 = (const float*)d_in[1];
    const float* beta1  = (const float*)d_in[2];
    const float* qkv_w  = (const float*)d_in[3];
    const float* qkv_b  = (const float*)d_in[4];
    const float* proj_w = (const float*)d_in[5];
    const float* proj_b = (const float*)d_in[6];
    const float* btab   = (const float*)d_in[7];
    const float* gamma2 = (const float*)d_in[8];
    const float* beta2  = (const float*)d_in[9];
    const float* fc1_w  = (const float*)d_in[10];
    const float* fc1_b  = (const float*)d_in[11];
    const float* fc2_w  = (const float*)d_in[12];
    const float* fc2_b  = (const float*)d_in[13];
    float* out = (float*)d_out;

    // ws budget EXACTLY kTok*768*2 B. d_out (77 MB fp32) doubles as scratch
    // until the mega kernel: qkv_t | bm_tab | qkv_bs | vT(50.3 MB).
    u16* buf_a = (u16*)d_ws;                      // kTok*192 bf16
    u16* buf_b = buf_a + (size_t)kTok * 192;      // kTok*576 bf16 (q,k used)
    u16* qkv_t = (u16*)d_out;                     // 110592 u16
    float* bm_tab = (float*)d_out + 55296;        // 57624 f32
    float* qkv_bs = bm_tab + 57624;               // 576 f32
    u16* vT = (u16*)d_out + 230400;               // 2048*6*32*64 u16, 16B-aligned
    u16* wt2   = (u16*)d_ws + (size_t)kTok * 768 - 331776;
    u16* proj_t = wt2;
    u16* f1_t   = wt2 + 36864;
    u16* f2_t   = f1_t + 147456;
    // rowmap: start of buf_b (qkv q,k dead after attn; written by wprep_rest
    // which is stream-ordered after attn). 100352 ints = 392 KB, far from wt2.
    int* rowmap = (int*)buf_b;

    // 0) prep: qkv weights (q pre-scaled), bias+mask table, scaled qkv bias
    wprep_qkv<<<(110592 + 255) / 256, 256, 0, stream>>>(qkv_w, qkv_t);
    prep_bm<<<(57624 + 255) / 256, 256, 0, stream>>>(btab, qkv_b, bm_tab, qkv_bs);
    // 1) LN1 + cyclic shift + window partition
    ln_kernel<<<kTok / 4, 256, 0, stream>>>(x, gamma1, beta1, buf_a, 1);
    // 2) qkv GEMM -> q,k rows in buf_b; v scattered transposed into vT
    gemm_mfma<5, 192, 3><<<kTok / 64, 256, 0, stream>>>(
        buf_a, qkv_t, 192, qkv_bs, nullptr, buf_b, vT);
    // 3) MFMA window attention -> buf_a (bf16)
    attn_mfma<<<(kNWin * kNH) / 4, 256, 0, stream>>>(buf_b, vT, bm_tab, buf_a);
    // 4) remaining weight prep + rowmap (qkv q,k dead now)
    wprep_rest<<<(331776 + kTok + 255) / 256, 256, 0, stream>>>(
        proj_w, fc1_w, fc2_w, proj_t, f1_t, f2_t, rowmap);
    // 5) MEGA: proj + residual gather + LN2 + MLP + residual scatter
    proj_mlp_fused<<<kTok / 64, 256, 0, stream>>>(
        buf_a, proj_t, proj_b, x, rowmap,
        gamma2, beta2, f1_t, fc1_b, f2_t, fc2_b, out);
}

// Round 7
// 484.094 us; speedup vs baseline: 1.4567x; 1.0290x over previous
//
#include <hip/hip_runtime.h>
#include <math.h>

namespace {
constexpr int kBatch = 32, kH = 56, kW = 56, kC = 192, kNH = 6, kWS = 7, kSS = 3;
constexpr int kL   = kH * kW;        // 3136
constexpr int kN   = kWS * kWS;      // 49
constexpr int kTok = kBatch * kL;    // 100352
constexpr int kNWin = kTok / kN;     // 2048 windows
constexpr float kEps   = 1e-3f;
constexpr float kScale = 0.17677669529663687f;  // HD^-0.5
}

typedef unsigned short u16;
typedef __attribute__((ext_vector_type(8))) short short8;   // 8 x bf16 (4 VGPRs)
typedef __attribute__((ext_vector_type(4))) float f32x4;    // MFMA accumulator

__device__ __forceinline__ float bf2f(u16 u) {
    return __uint_as_float(((unsigned int)u) << 16);
}
__device__ __forceinline__ u16 f2bf(float f) {  // round-to-nearest-even
    unsigned int x = __float_as_uint(f);
    return (u16)((x + 0x7FFFu + ((x >> 16) & 1u)) >> 16);
}
// tanh-approx GELU. |err vs exact erf-GELU| < 5e-4 everywhere; bf16 output
// rounding dominates. HW v_exp_f32 instead of libm erff.
__device__ __forceinline__ float gelu_f(float x) {
    float z = 0.7978845608028654f * x * (1.0f + 0.044715f * x * x);
    float t = 1.0f - 2.0f / (1.0f + __expf(2.0f * z));
    return 0.5f * x * (1.0f + t);
}

// window row index -> spatial token (inverse cyclic shift + window reverse).
__device__ __forceinline__ int win_row_to_tok(int idx) {
    const int win = idx / kN, n = idx - win * kN;
    const int b = win >> 6, wi = win & 63;
    const int wh = wi >> 3, ww = wi & 7;
    const int i1 = n / kWS, j1 = n - i1 * kWS;
    const int h = (wh * kWS + i1 + kSS) % kH;
    const int w = (ww * kWS + j1 + kSS) % kW;
    return b * kL + h * kW + w;
}

// ---------------------------------------------------------------------------
// Weight prep. qkv: fp32 (192 x 576) -> bf16 n-major (576 x 192), q-cols
// pre-scaled by kScale.
// ---------------------------------------------------------------------------
__global__ __launch_bounds__(256) void wprep_qkv(
    const float* __restrict__ w, u16* __restrict__ wt)
{
    const int idx = blockIdx.x * 256 + threadIdx.x;
    if (idx >= 576 * 192) return;
    const int n = idx / 192, k = idx - n * 192;
    float v = w[(size_t)k * 576 + n];
    if (n < 192) v *= kScale;
    wt[idx] = f2bf(v);
}

__global__ __launch_bounds__(256) void wprep_rest(
    const float* __restrict__ pw, const float* __restrict__ f1w,
    const float* __restrict__ f2w, u16* __restrict__ proj_t,
    u16* __restrict__ f1_t, u16* __restrict__ f2_t)
{
    int idx = blockIdx.x * 256 + threadIdx.x;
    if (idx < 36864) {
        const int n = idx / 192, k = idx - n * 192;
        proj_t[idx] = f2bf(pw[(size_t)k * 192 + n]);
        return;
    }
    idx -= 36864;
    if (idx < 147456) {
        const int n = idx / 192, k = idx - n * 192;
        f1_t[idx] = f2bf(f1w[(size_t)k * 768 + n]);
        return;
    }
    idx -= 147456;
    if (idx < 147456) {
        const int n = idx / 768, k = idx - n * 768;
        f2_t[idx] = f2bf(f2w[(size_t)k * 192 + n]);
    }
}

// ---------------------------------------------------------------------------
// Bias+mask table T[cls][head][n][m] (mask folded, used as MFMA C-init) and
// scaled qkv bias copy (q-part * kScale).
// ---------------------------------------------------------------------------
__global__ __launch_bounds__(256) void prep_bm(
    const float* __restrict__ btab, const float* __restrict__ qkv_b,
    float* __restrict__ T, float* __restrict__ qkv_bs)
{
    const int idx = blockIdx.x * 256 + threadIdx.x;
    if (idx < 576) qkv_bs[idx] = (idx < 192) ? qkv_b[idx] * kScale : qkv_b[idx];
    if (idx >= 4 * 6 * 49 * 49) return;
    const int m = idx % 49, n = (idx / 49) % 49;
    const int head = (idx / 2401) % 6, cls = idx / (2401 * 6);
    const int i1 = n / 7, j1 = n % 7, i2 = m / 7, j2 = m % 7;
    float v = btab[((i1 - i2 + 6) * 13 + (j1 - j2 + 6)) * kNH + head];
    const int whE = cls >> 1, wwE = cls & 1;
    const int r1 = (whE ? (i1 < 4 ? 1 : 2) : 0) * 3 + (wwE ? (j1 < 4 ? 1 : 2) : 0);
    const int r2 = (whE ? (i2 < 4 ? 1 : 2) : 0) * 3 + (wwE ? (j2 < 4 ? 1 : 2) : 0);
    if (r1 != r2) v -= 100.f;
    T[idx] = v;
}

// ---------------------------------------------------------------------------
// Fused LN1 + qkv GEMM, one block per 64 window-ordered rows.
// Stage: gather x rows via inverse-shift map, LN1 -> As (bf16). Replaces the
// standalone ln_kernel (one less launch + 115 MB LN round-trip; A is read
// once here anyway so the fused gather is traffic-neutral for this kernel).
// GEMM: q,k -> qk_out rows of 576 (cols 0..383); v -> vt TRANSPOSED
// [(win*6+head)*32 + d][64] for the attention PV B-fragments.
// ---------------------------------------------------------------------------
__global__ __launch_bounds__(256) void ln_qkv(
    const float* __restrict__ x, const float* __restrict__ gamma,
    const float* __restrict__ beta,
    const u16* __restrict__ qkv_t, const float* __restrict__ qkv_bs,
    u16* __restrict__ qk_out, u16* __restrict__ vt)
{
    constexpr int Kp = 200;
    __shared__ u16 As[64 * Kp];
    __shared__ int rowsrc[64];
    const int tid  = threadIdx.x;
    const int wave = tid >> 6, lane = tid & 63;
    const int quad = lane >> 4, l15 = lane & 15;
    const int m0 = blockIdx.x * 64;

    if (tid < 64) rowsrc[tid] = win_row_to_tok(m0 + tid);
    __syncthreads();

    // ---- LN1: 16 lanes/row, 4 rows/wave/round, 4 rounds -> As bf16 ----
    {
        float gv[12], bv[12];
        #pragma unroll
        for (int j = 0; j < 12; ++j) {
            gv[j] = gamma[l15 * 12 + j];
            bv[j] = beta[l15 * 12 + j];
        }
        #pragma unroll
        for (int it = 0; it < 4; ++it) {
            const int r = it * 16 + wave * 4 + quad;
            const float* xp = x + (size_t)rowsrc[r] * kC + l15 * 12;
            float4 u0 = *(const float4*)(xp);
            float4 u1 = *(const float4*)(xp + 4);
            float4 u2 = *(const float4*)(xp + 8);
            float v[12] = {u0.x, u0.y, u0.z, u0.w, u1.x, u1.y, u1.z, u1.w,
                           u2.x, u2.y, u2.z, u2.w};
            float s = 0.f, sq = 0.f;
            #pragma unroll
            for (int j = 0; j < 12; ++j) { s += v[j]; sq += v[j] * v[j]; }
            #pragma unroll
            for (int off = 1; off < 16; off <<= 1) {
                s  += __shfl_xor(s, off, 64);
                sq += __shfl_xor(sq, off, 64);
            }
            const float mean = s * (1.0f / kC);
            const float inv  = rsqrtf(sq * (1.0f / kC) - mean * mean + kEps);
            unsigned* ap = (unsigned*)&As[r * Kp + l15 * 12];
            #pragma unroll
            for (int j = 0; j < 6; ++j) {
                float a0 = (v[2 * j]     - mean) * inv * gv[2 * j]     + bv[2 * j];
                float a1 = (v[2 * j + 1] - mean) * inv * gv[2 * j + 1] + bv[2 * j + 1];
                ap[j] = (unsigned)f2bf(a0) | ((unsigned)f2bf(a1) << 16);
            }
        }
    }
    __syncthreads();

    // ---- qkv GEMM: 3 x 192 output cols ----
    #pragma unroll
    for (int j = 0; j < 3; ++j) {
        const int nb0 = j * 192 + wave * 48;
        const u16* Bbase = qkv_t + (size_t)(nb0 + l15) * 192 + quad * 8;
        f32x4 acc[4][3] = {};
        #pragma unroll
        for (int ks = 0; ks < 6; ++ks) {
            short8 a[4], b[3];
            #pragma unroll
            for (int i = 0; i < 4; ++i)
                a[i] = *(const short8*)&As[(i * 16 + l15) * Kp + ks * 32 + quad * 8];
            #pragma unroll
            for (int t = 0; t < 3; ++t)
                b[t] = *(const short8*)(Bbase + (size_t)t * 16 * 192 + ks * 32);
            #pragma unroll
            for (int i = 0; i < 4; ++i)
                #pragma unroll
                for (int t = 0; t < 3; ++t)
                    acc[i][t] = __builtin_amdgcn_mfma_f32_16x16x32_bf16(
                        a[i], b[t], acc[i][t], 0, 0, 0);
        }
        float bcol[3];
        #pragma unroll
        for (int t = 0; t < 3; ++t) bcol[t] = qkv_bs[nb0 + t * 16 + l15];
        #pragma unroll
        for (int i = 0; i < 4; ++i) {
            #pragma unroll
            for (int reg = 0; reg < 4; ++reg) {
                const int r = m0 + i * 16 + quad * 4 + reg;
                if (j == 2) {
                    // scatter v transposed: row win*6*32 + head*32 + d, col n
                    const int win = r / kN, n = r - win * kN;
                    #pragma unroll
                    for (int t = 0; t < 3; ++t) {
                        const int d = nb0 - 384 + t * 16 + l15;
                        const size_t off =
                            ((size_t)win * 192 + d) * 64 + n;  // 192 = 6*32
                        vt[off] = f2bf(acc[i][t][reg] + bcol[t]);
                    }
                } else {
                    #pragma unroll
                    for (int t = 0; t < 3; ++t) {
                        const int c = nb0 + t * 16 + l15;
                        qk_out[(size_t)r * 576 + c] =
                            f2bf(acc[i][t][reg] + bcol[t]);
                    }
                }
            }
        }
    }
}

// ---------------------------------------------------------------------------
// MEGA: proj GEMM + residual gather + LN2 + MLP + scatter, one block/64 rows.
//   x1 = x[spatial] + attnout @ proj_w + proj_b      (48 f32 REGS, no HBM)
//   out[spatial]   = x1 + fc2(gelu(fc1(LN(x1))))
// v7: + register double-buffer of B-frags in proj/fc1/fc2 ks-loops (clean
// retry of the round-4 prefetch hypothesis, WITHOUT any launch-bounds
// min-occ arg — rounds 2-4 showed that clamps VGPR below live state).
// ---------------------------------------------------------------------------
__global__ __launch_bounds__(256) void proj_mlp_fused(
    const u16* __restrict__ A,        // attn out (window-ordered rows, bf16)
    const u16* __restrict__ proj_t, const float* __restrict__ proj_b,
    const float* __restrict__ x,      // residual-1 source (spatial order)
    const float* __restrict__ gamma, const float* __restrict__ beta,
    const u16* __restrict__ f1_t, const float* __restrict__ fc1_b,
    const u16* __restrict__ f2_t, const float* __restrict__ fc2_b,
    float* __restrict__ out)
{
    constexpr int Kp = 200;   // As row pitch (u16)
    constexpr int Hp = 200;   // Hs row pitch (u16)
    __shared__ u16 As[64 * Kp];   // 25600 B: attn-out tile, then LN2 output
    __shared__ u16 Hs[64 * Hp];   // 25600 B: LN stats overlay, then hidden
    __shared__ int rowdest[64];
    const int tid  = threadIdx.x;
    const int wave = tid >> 6, lane = tid & 63;
    const int quad = lane >> 4, l15 = lane & 15;
    const int m0 = blockIdx.x * 64;
    float* Hsf = (float*)Hs;      // stats overlay (first 2560 B)

    // ---- stage attn-out tile + rowdest ----
    {
        const u16* src = A + (size_t)m0 * 192;
        #pragma unroll
        for (int i = tid; i < 64 * 192 / 8; i += 256) {
            const int e = i * 8;
            const int r = e / 192, c = e - r * 192;
            *(short8*)&As[r * Kp + c] = *(const short8*)(src + e);
        }
        if (tid < 64) rowdest[tid] = win_row_to_tok(m0 + tid);
    }
    __syncthreads();

    // ---- residual gather (issued early; latency hides under proj GEMM) ----
    float x1[4][3][4];
    #pragma unroll
    for (int i = 0; i < 4; ++i) {
        #pragma unroll
        for (int reg = 0; reg < 4; ++reg) {
            const float* xr = x + (size_t)rowdest[i * 16 + quad * 4 + reg] * kC
                              + wave * 48 + l15;
            #pragma unroll
            for (int t = 0; t < 3; ++t) x1[i][t][reg] = xr[t * 16];
        }
    }

    // ---- proj GEMM: acc = As @ proj_t (cols wave*48..+48), K=192 ----
    f32x4 acc[4][3] = {};
    {
        const u16* Bbase = proj_t + (size_t)(wave * 48 + l15) * 192 + quad * 8;
        short8 bc[3], bn[3];
        #pragma unroll
        for (int t = 0; t < 3; ++t)
            bc[t] = *(const short8*)(Bbase + (size_t)t * 16 * 192);
        #pragma unroll
        for (int ks = 0; ks < 6; ++ks) {
            if (ks < 5) {
                #pragma unroll
                for (int t = 0; t < 3; ++t)
                    bn[t] = *(const short8*)(Bbase + (size_t)t * 16 * 192 +
                                             (ks + 1) * 32);
            }
            short8 a[4];
            #pragma unroll
            for (int i = 0; i < 4; ++i)
                a[i] = *(const short8*)&As[(i * 16 + l15) * Kp + ks * 32 + quad * 8];
            #pragma unroll
            for (int i = 0; i < 4; ++i)
                #pragma unroll
                for (int t = 0; t < 3; ++t)
                    acc[i][t] = __builtin_amdgcn_mfma_f32_16x16x32_bf16(
                        a[i], bc[t], acc[i][t], 0, 0, 0);
            if (ks < 5) {
                #pragma unroll
                for (int t = 0; t < 3; ++t) bc[t] = bn[t];
            }
        }
    }
    // ---- x1 = x + proj + bias (registers only) ----
    {
        float bcol[3];
        #pragma unroll
        for (int t = 0; t < 3; ++t) bcol[t] = proj_b[wave * 48 + t * 16 + l15];
        #pragma unroll
        for (int i = 0; i < 4; ++i)
            #pragma unroll
            for (int t = 0; t < 3; ++t)
                #pragma unroll
                for (int reg = 0; reg < 4; ++reg)
                    x1[i][t][reg] += acc[i][t][reg] + bcol[t];
    }

    // ---- LN2 partials: sum over this wave's 48 cols per row -> Hs stats ----
    #pragma unroll
    for (int i = 0; i < 4; ++i) {
        #pragma unroll
        for (int reg = 0; reg < 4; ++reg) {
            float s  = x1[i][0][reg] + x1[i][1][reg] + x1[i][2][reg];
            float sq = x1[i][0][reg] * x1[i][0][reg]
                     + x1[i][1][reg] * x1[i][1][reg]
                     + x1[i][2][reg] * x1[i][2][reg];
            #pragma unroll
            for (int off = 1; off < 16; off <<= 1) {
                s  += __shfl_xor(s, off, 64);
                sq += __shfl_xor(sq, off, 64);
            }
            if (l15 == 0) {
                const int r = i * 16 + quad * 4 + reg;
                Hsf[r * 8 + wave * 2]     = s;
                Hsf[r * 8 + wave * 2 + 1] = sq;
            }
        }
    }
    __syncthreads();   // also: all As GEMM reads complete
    if (tid < 64) {
        const float s  = Hsf[tid * 8] + Hsf[tid * 8 + 2] + Hsf[tid * 8 + 4] + Hsf[tid * 8 + 6];
        const float sq = Hsf[tid * 8 + 1] + Hsf[tid * 8 + 3] + Hsf[tid * 8 + 5] + Hsf[tid * 8 + 7];
        const float mean = s * (1.0f / kC);
        const float inv  = rsqrtf(sq * (1.0f / kC) - mean * mean + kEps);
        Hsf[512 + tid * 2]     = mean;
        Hsf[512 + tid * 2 + 1] = inv;
    }
    __syncthreads();
    // ---- LN2 output -> As (bf16) ----
    {
        float gv[3], bv[3];
        #pragma unroll
        for (int t = 0; t < 3; ++t) {
            gv[t] = gamma[wave * 48 + t * 16 + l15];
            bv[t] = beta[wave * 48 + t * 16 + l15];
        }
        #pragma unroll
        for (int i = 0; i < 4; ++i) {
            #pragma unroll
            for (int reg = 0; reg < 4; ++reg) {
                const int r = i * 16 + quad * 4 + reg;
                const float mean = Hsf[512 + r * 2];
                const float inv  = Hsf[513 + r * 2];
                #pragma unroll
                for (int t = 0; t < 3; ++t)
                    As[r * Kp + wave * 48 + t * 16 + l15] =
                        f2bf((x1[i][t][reg] - mean) * inv * gv[t] + bv[t]);
            }
        }
    }
    __syncthreads();

    // ---- MLP: 4 chunks of 192 hidden cols ----
    f32x4 acc2[4][3] = {};
    for (int c = 0; c < 4; ++c) {
        f32x4 acc1[4][3] = {};
        {
            const u16* B1 = f1_t + (size_t)(c * 192 + wave * 48 + l15) * 192 + quad * 8;
            short8 bc[3], bn[3];
            #pragma unroll
            for (int t = 0; t < 3; ++t)
                bc[t] = *(const short8*)(B1 + (size_t)t * 16 * 192);
            #pragma unroll
            for (int ks = 0; ks < 6; ++ks) {
                if (ks < 5) {
                    #pragma unroll
                    for (int t = 0; t < 3; ++t)
                        bn[t] = *(const short8*)(B1 + (size_t)t * 16 * 192 +
                                                 (ks + 1) * 32);
                }
                short8 a[4];
                #pragma unroll
                for (int i = 0; i < 4; ++i)
                    a[i] = *(const short8*)&As[(i * 16 + l15) * Kp + ks * 32 + quad * 8];
                #pragma unroll
                for (int i = 0; i < 4; ++i)
                    #pragma unroll
                    for (int t = 0; t < 3; ++t)
                        acc1[i][t] = __builtin_amdgcn_mfma_f32_16x16x32_bf16(
                            a[i], bc[t], acc1[i][t], 0, 0, 0);
                if (ks < 5) {
                    #pragma unroll
                    for (int t = 0; t < 3; ++t) bc[t] = bn[t];
                }
            }
        }
        __syncthreads();   // c>0: all waves done reading Hs chunk c-1
        #pragma unroll
        for (int t = 0; t < 3; ++t) {
            const int cc = wave * 48 + t * 16 + l15;
            const float bb = fc1_b[c * 192 + cc];
            #pragma unroll
            for (int i = 0; i < 4; ++i) {
                #pragma unroll
                for (int reg = 0; reg < 4; ++reg) {
                    const int r = i * 16 + quad * 4 + reg;
                    Hs[r * Hp + cc] = f2bf(gelu_f(acc1[i][t][reg] + bb));
                }
            }
        }
        __syncthreads();
        {
            const u16* B2 = f2_t + (size_t)(wave * 48 + l15) * 768 + c * 192 + quad * 8;
            short8 bc[3], bn[3];
            #pragma unroll
            for (int t = 0; t < 3; ++t)
                bc[t] = *(const short8*)(B2 + (size_t)t * 16 * 768);
            #pragma unroll
            for (int ks = 0; ks < 6; ++ks) {
                if (ks < 5) {
                    #pragma unroll
                    for (int t = 0; t < 3; ++t)
                        bn[t] = *(const short8*)(B2 + (size_t)t * 16 * 768 +
                                                 (ks + 1) * 32);
                }
                short8 a[4];
                #pragma unroll
                for (int i = 0; i < 4; ++i)
                    a[i] = *(const short8*)&Hs[(i * 16 + l15) * Hp + ks * 32 + quad * 8];
                #pragma unroll
                for (int i = 0; i < 4; ++i)
                    #pragma unroll
                    for (int t = 0; t < 3; ++t)
                        acc2[i][t] = __builtin_amdgcn_mfma_f32_16x16x32_bf16(
                            a[i], bc[t], acc2[i][t], 0, 0, 0);
                if (ks < 5) {
                    #pragma unroll
                    for (int t = 0; t < 3; ++t) bc[t] = bn[t];
                }
            }
        }
    }
    // ---- epilogue: out[spatial] = x1 + acc2 + fc2_b ----
    #pragma unroll
    for (int t = 0; t < 3; ++t) {
        const int cc = wave * 48 + t * 16 + l15;
        const float bb = fc2_b[cc];
        #pragma unroll
        for (int i = 0; i < 4; ++i) {
            #pragma unroll
            for (int reg = 0; reg < 4; ++reg) {
                const int dr = rowdest[i * 16 + quad * 4 + reg];
                out[(size_t)dr * kC + cc] = x1[i][t][reg] + acc2[i][t][reg] + bb;
            }
        }
    }
}

// ---------------------------------------------------------------------------
// MFMA window attention v2: ONE WAVE per (window, head).
// ---------------------------------------------------------------------------
__global__ __launch_bounds__(256) void attn_mfma(
    const u16* __restrict__ qkv, const u16* __restrict__ vt,
    const float* __restrict__ T, u16* __restrict__ out)
{
    __shared__ u16 Ps[4][64][72];
    const int tid = threadIdx.x;
    const int wave = tid >> 6, lane = tid & 63;
    const int quad = lane >> 4, l15 = lane & 15;
    const int pair = blockIdx.x * 4 + wave;
    const int win = pair / 6, head = pair - win * 6;
    const int wi = win & 63;
    const int cls = (((wi >> 3) == 7) ? 2 : 0) + (((wi & 7) == 7) ? 1 : 0);
    const float* Tb = T + (size_t)(cls * 6 + head) * 49 * 49;

    const u16* base = qkv + (size_t)win * 49 * 576 + head * 32 + quad * 8;
    short8 zz = {};
    short8 qa[4], kb[4];
    #pragma unroll
    for (int i = 0; i < 4; ++i) {
        const int n = i * 16 + l15;
        qa[i] = (n < 49) ? *(const short8*)(base + (size_t)n * 576) : zz;
        kb[i] = (n < 49) ? *(const short8*)(base + (size_t)n * 576 + 192) : zz;
    }
    f32x4 acc[4][4];
    #pragma unroll
    for (int i = 0; i < 4; ++i) {
        #pragma unroll
        for (int reg = 0; reg < 4; ++reg) {
            const int n = i * 16 + quad * 4 + reg;
            const bool nv = (n < 49);
            const float* Trow = Tb + (nv ? n : 0) * 49;
            #pragma unroll
            for (int j = 0; j < 3; ++j)
                acc[i][j][reg] = nv ? Trow[j * 16 + l15] : 0.f;
            acc[i][3][reg] = (nv && l15 == 0) ? Trow[48] : -30000.f;
        }
    }
    #pragma unroll
    for (int i = 0; i < 4; ++i)
        #pragma unroll
        for (int j = 0; j < 4; ++j)
            acc[i][j] = __builtin_amdgcn_mfma_f32_16x16x32_bf16(
                qa[i], kb[j], acc[i][j], 0, 0, 0);
    float rowinv[4][4];
    #pragma unroll
    for (int i = 0; i < 4; ++i) {
        #pragma unroll
        for (int reg = 0; reg < 4; ++reg) {
            const int n = i * 16 + quad * 4 + reg;
            float e0 = __expf(acc[i][0][reg]), e1 = __expf(acc[i][1][reg]);
            float e2 = __expf(acc[i][2][reg]), e3 = __expf(acc[i][3][reg]);
            float sum = e0 + e1 + e2 + e3;
            #pragma unroll
            for (int off = 1; off < 16; off <<= 1)
                sum += __shfl_xor(sum, off, 64);
            rowinv[i][reg] = 1.0f / sum;
            Ps[wave][n][0 * 16 + l15] = f2bf(e0);
            Ps[wave][n][1 * 16 + l15] = f2bf(e1);
            Ps[wave][n][2 * 16 + l15] = f2bf(e2);
            Ps[wave][n][3 * 16 + l15] = f2bf(e3);
        }
    }
    const u16* vb_base = vt + ((size_t)pair * 32 + l15) * 64 + quad * 8;
    f32x4 o[4][2] = {};
    #pragma unroll
    for (int ks = 0; ks < 2; ++ks) {
        short8 pa[4], vb[2];
        #pragma unroll
        for (int i = 0; i < 4; ++i)
            pa[i] = *(const short8*)&Ps[wave][i * 16 + l15][ks * 32 + quad * 8];
        #pragma unroll
        for (int t = 0; t < 2; ++t)
            vb[t] = *(const short8*)(vb_base + (size_t)t * 16 * 64 + ks * 32);
        #pragma unroll
        for (int i = 0; i < 4; ++i)
            #pragma unroll
            for (int t = 0; t < 2; ++t)
                o[i][t] = __builtin_amdgcn_mfma_f32_16x16x32_bf16(
                    pa[i], vb[t], o[i][t], 0, 0, 0);
    }
    u16* obase = out + (size_t)win * 49 * 192 + head * 32;
    #pragma unroll
    for (int i = 0; i < 4; ++i) {
        #pragma unroll
        for (int reg = 0; reg < 4; ++reg) {
            const int n = i * 16 + quad * 4 + reg;
            if (n < 49) {
                const float inv = rowinv[i][reg];
                obase[(size_t)n * 192 + l15]      = f2bf(o[i][0][reg] * inv);
                obase[(size_t)n * 192 + 16 + l15] = f2bf(o[i][1][reg] * inv);
            }
        }
    }
}

// ---------------------------------------------------------------------------
extern "C" void kernel_launch(void* const* d_in, const int* in_sizes, int n_in,
                              void* d_out, int out_size, void* d_ws, size_t ws_size,
                              hipStream_t stream)
{
    const float* x      = (const float*)d_in[0];
    const float* gamma1 = (const float*)d_in[1];
    const float* beta1  = (const float*)d_in[2];
    const float* qkv_w  = (const float*)d_in[3];
    const float* qkv_b  = (const float*)d_in[4];
    const float* proj_w = (const float*)d_in[5];
    const float* proj_b = (const float*)d_in[6];
    const float* btab   = (const float*)d_in[7];
    const float* gamma2 = (const float*)d_in[8];
    const float* beta2  = (const float*)d_in[9];
    const float* fc1_w  = (const float*)d_in[10];
    const float* fc1_b  = (const float*)d_in[11];
    const float* fc2_w  = (const float*)d_in[12];
    const float* fc2_b  = (const float*)d_in[13];
    float* out = (float*)d_out;

    // ws budget EXACTLY kTok*768*2 B. d_out (77 MB fp32) doubles as scratch
    // until the mega kernel: qkv_t | bm_tab | qkv_bs | vT(50.3 MB).
    u16* buf_a = (u16*)d_ws;                      // kTok*192 bf16 (attn out)
    u16* buf_b = buf_a + (size_t)kTok * 192;      // kTok*576 bf16 (q,k used)
    u16* qkv_t = (u16*)d_out;                     // 110592 u16
    float* bm_tab = (float*)d_out + 55296;        // 57624 f32
    float* qkv_bs = bm_tab + 57624;               // 576 f32
    u16* vT = (u16*)d_out + 230400;               // 2048*6*32*64 u16, 16B-aligned
    u16* wt2   = (u16*)d_ws + (size_t)kTok * 768 - 331776;
    u16* proj_t = wt2;
    u16* f1_t   = wt2 + 36864;
    u16* f2_t   = f1_t + 147456;

    // 0) prep: qkv weights (q pre-scaled), bias+mask table, scaled qkv bias
    wprep_qkv<<<(110592 + 255) / 256, 256, 0, stream>>>(qkv_w, qkv_t);
    prep_bm<<<(57624 + 255) / 256, 256, 0, stream>>>(btab, qkv_b, bm_tab, qkv_bs);
    // 1) fused LN1 + shift-gather + qkv GEMM -> q,k in buf_b; v -> vT
    ln_qkv<<<kTok / 64, 256, 0, stream>>>(
        x, gamma1, beta1, qkv_t, qkv_bs, buf_b, vT);
    // 2) MFMA window attention -> buf_a (bf16)
    attn_mfma<<<(kNWin * kNH) / 4, 256, 0, stream>>>(buf_b, vT, bm_tab, buf_a);
    // 3) remaining weight prep into buf_b tail (qkv q,k dead now)
    wprep_rest<<<(331776 + 255) / 256, 256, 0, stream>>>(
        proj_w, fc1_w, fc2_w, proj_t, f1_t, f2_t);
    // 4) MEGA: proj + residual gather + LN2 + MLP + residual scatter
    proj_mlp_fused<<<kTok / 64, 256, 0, stream>>>(
        buf_a, proj_t, proj_b, x,
        gamma2, beta2, f1_t, fc1_b, f2_t, fc2_b, out);
}